// Round 5
// baseline (1251.031 us; speedup 1.0000x reference)
//
#include <hip/hip_runtime.h>

#define NB 4096      // N = H*W
#define BATCH 4
#define CD 256       // channels
#define ED 64        // embedding dim
#define KNN 24

typedef __attribute__((ext_vector_type(8))) short bf16x8;
typedef __attribute__((ext_vector_type(4))) float f32x4;

__device__ __forceinline__ unsigned short f2bf(float x) {
  unsigned u = __float_as_uint(x);
  unsigned r = (u + 0x7fffu + ((u >> 16) & 1u)) >> 16;
  return (unsigned short)r;
}

// ---------------- K1: emb = x @ dist_w^T  -> emb_hl (bf16 hi/lo, XOR-swizzled chunks) + sq (fp32)
__global__ __launch_bounds__(256) void k_emb(const float* __restrict__ x,
                                             const float* __restrict__ dist_w,
                                             unsigned* __restrict__ emb_hl,
                                             float* __restrict__ sq) {
  __shared__ float wds[ED * CD];   // 64 KB
  __shared__ float red[64 * 4];
  const int b = blockIdx.x >> 6;
  const int n0 = (blockIdx.x & 63) << 6;
  const int tid = threadIdx.x;
  const float4* wsrc = (const float4*)dist_w;
  float4* wdst = (float4*)wds;
#pragma unroll
  for (int k = 0; k < 16; ++k) wdst[tid + 256 * k] = wsrc[tid + 256 * k];
  __syncthreads();
  const int eg = tid >> 6;   // 0..3
  const int nl = tid & 63;
  const int n = n0 + nl;
  float acc[16];
#pragma unroll
  for (int t = 0; t < 16; ++t) acc[t] = 0.f;
  const float* xb = x + (size_t)b * CD * NB + n;
#pragma unroll 4
  for (int c = 0; c < CD; ++c) {
    float xv = xb[(size_t)c * NB];
#pragma unroll
    for (int t = 0; t < 16; ++t)
      acc[t] = fmaf(xv, wds[(eg * 16 + t) * CD + c], acc[t]);
  }
  float s = 0.f;
#pragma unroll
  for (int t = 0; t < 16; ++t) s = fmaf(acc[t], acc[t], s);
  unsigned hw[8], lw[8];
#pragma unroll
  for (int i = 0; i < 8; ++i) {
    unsigned short h0 = f2bf(acc[2 * i]);
    unsigned short h1 = f2bf(acc[2 * i + 1]);
    float l0f = acc[2 * i] - __uint_as_float((unsigned)h0 << 16);
    float l1f = acc[2 * i + 1] - __uint_as_float((unsigned)h1 << 16);
    hw[i] = (unsigned)h0 | ((unsigned)h1 << 16);
    lw[i] = (unsigned)f2bf(l0f) | ((unsigned)f2bf(l1f) << 16);
  }
  uint4* g = (uint4*)emb_hl;
  const size_t gb = ((size_t)(b * NB + n)) * 16;
  const int k15 = n & 15;
  g[gb + ((2 * eg) ^ k15)]     = make_uint4(hw[0], hw[1], hw[2], hw[3]);
  g[gb + ((2 * eg + 1) ^ k15)] = make_uint4(hw[4], hw[5], hw[6], hw[7]);
  g[gb + ((8 + 2 * eg) ^ k15)]     = make_uint4(lw[0], lw[1], lw[2], lw[3]);
  g[gb + ((8 + 2 * eg + 1) ^ k15)] = make_uint4(lw[4], lw[5], lw[6], lw[7]);
  red[nl * 4 + eg] = s;
  __syncthreads();
  if (tid < 64)
    sq[b * NB + n0 + tid] = red[tid * 4] + red[tid * 4 + 1] + red[tid * 4 + 2] + red[tid * 4 + 3];
}

// ---------------- K2: X_lin[b,n,c] = sum_k x[b,k,n]*fc_w[c,k] + fc_b[c]
__global__ __launch_bounds__(256) void k_xlin(const float* __restrict__ x,
                                              const float* __restrict__ fc_w,
                                              const float* __restrict__ fc_b,
                                              float* __restrict__ xlin) {
  __shared__ float xt[64 * 64];     // [k][n]
  __shared__ float wt[64 * 260];    // [k][c] padded
  const int b = blockIdx.x >> 6;
  const int n0 = (blockIdx.x & 63) << 6;
  const int tid = threadIdx.x;
  const int nl4 = tid & 15;
  const int cg = tid >> 4;
  float acc[4][16];
#pragma unroll
  for (int i = 0; i < 4; ++i)
#pragma unroll
    for (int j = 0; j < 16; ++j) acc[i][j] = 0.f;

  for (int kt = 0; kt < 4; ++kt) {
    __syncthreads();
#pragma unroll 4
    for (int i = 0; i < 16; ++i) {
      int idx = tid + 256 * i;
      int k = idx >> 6, n = idx & 63;
      xt[idx] = x[((size_t)(b * CD + kt * 64 + k)) * NB + n0 + n];
    }
#pragma unroll 4
    for (int i = 0; i < 16; ++i) {
      int q = tid + 256 * i;
      int c = q >> 4, k4 = (q & 15) * 4;
      float4 v = *(const float4*)&fc_w[(size_t)c * CD + kt * 64 + k4];
      wt[(k4 + 0) * 260 + c] = v.x;
      wt[(k4 + 1) * 260 + c] = v.y;
      wt[(k4 + 2) * 260 + c] = v.z;
      wt[(k4 + 3) * 260 + c] = v.w;
    }
    __syncthreads();
#pragma unroll 2
    for (int k = 0; k < 64; ++k) {
      float4 xv = *(const float4*)&xt[k * 64 + 4 * nl4];
#pragma unroll
      for (int j = 0; j < 4; ++j) {
        float4 wv = *(const float4*)&wt[k * 260 + 4 * cg + 64 * j];
        const float* wp = &wv.x;
#pragma unroll
        for (int l = 0; l < 4; ++l) {
          acc[0][4 * j + l] = fmaf(xv.x, wp[l], acc[0][4 * j + l]);
          acc[1][4 * j + l] = fmaf(xv.y, wp[l], acc[1][4 * j + l]);
          acc[2][4 * j + l] = fmaf(xv.z, wp[l], acc[2][4 * j + l]);
          acc[3][4 * j + l] = fmaf(xv.w, wp[l], acc[3][4 * j + l]);
        }
      }
    }
  }
#pragma unroll
  for (int i = 0; i < 4; ++i) {
    int n = n0 + 4 * nl4 + i;
    float* dst = xlin + ((size_t)(b * NB + n)) * CD;
#pragma unroll
    for (int j = 0; j < 4; ++j) {
      int c = 4 * cg + 64 * j;
      float4 bv = *(const float4*)&fc_b[c];
      float4 o;
      o.x = acc[i][4 * j + 0] + bv.x;
      o.y = acc[i][4 * j + 1] + bv.y;
      o.z = acc[i][4 * j + 2] + bv.z;
      o.w = acc[i][4 * j + 3] + bv.w;
      *(float4*)&dst[c] = o;
    }
  }
}

// ---------------- K3 v5: MFMA Gram + register-resident top-24 (cswap bubble), threshold pre-filter
// 512 thr, 64 rows/block, 128-m chunks (32 chunks). LDS 98.6 KB (manual partition, phase-reused).
__global__ __launch_bounds__(512) void k_dist(const unsigned* __restrict__ emb_hl,
                                              const float* __restrict__ sq,
                                              int* __restrict__ row_idx,
                                              int* __restrict__ row_cnt,
                                              int* __restrict__ col_cnt) {
  __shared__ __align__(16) unsigned char smem[98816];
  unsigned* eN = (unsigned*)smem;                        // 16384 B (64 rows x 64 u32, swizzled)
  unsigned* eM = (unsigned*)(smem + 16384);              // 32768 B (128 rows)
  float* d2f   = (float*)(smem + 49152);                 // 33024 B (64 x 129 f32)
  float* sqA   = (float*)(smem + 82432);                 // 16384 B (all 4096 sq)
  unsigned long long* dump = (unsigned long long*)smem;  // phase 2: 98304 B (8 seg x 64 row x 24)

  const int b = blockIdx.x >> 6;
  const int n0 = (blockIdx.x & 63) << 6;
  const int tid = threadIdx.x;
  const uint4* embg = (const uint4*)emb_hl;
  const size_t bbase = (size_t)b * NB;

  // stage eN (64 rows x 16 uint4) + all sq for this batch
#pragma unroll
  for (int k = 0; k < 2; ++k) {
    int q = tid + 512 * k;
    int r = q >> 4, ch = q & 15;
    *(uint4*)&eN[r * 64 + ch * 4] = embg[(bbase + n0 + r) * 16 + ch];
  }
#pragma unroll
  for (int k = 0; k < 8; ++k) sqA[tid + 512 * k] = sq[b * NB + tid + 512 * k];
  __syncthreads();

  const int w = tid >> 6, lane = tid & 63;
  const int quad = lane >> 4, lr = lane & 15;
  const int rt = w >> 1;              // row tile 0..3 (rows rt*16..+15)
  const int cg = w & 1;               // col half (cols cg*64..+63 as 4 tiles of 16)
  const int rowA = rt * 16 + lr;

  const int seg = tid >> 6;           // drain segment 0..7
  const int dr = tid & 63;            // drain row
  const int mb = seg * 16;

  unsigned long long lst[24];
#pragma unroll
  for (int i = 0; i < 24; ++i) lst[i] = ~0ULL;

  for (int ci = 0; ci < 32; ++ci) {
    const int m0 = ci << 7;
    // stage eM: 128 rows x 16 uint4
#pragma unroll
    for (int k = 0; k < 4; ++k) {
      int q = tid + 512 * k;
      int r = q >> 4, ch = q & 15;
      *(uint4*)&eM[r * 64 + ch * 4] = embg[(bbase + m0 + r) * 16 + ch];
    }
    __syncthreads();  // B1: eM ready AND previous drain done (d2f free)

    f32x4 acc[4];
#pragma unroll
    for (int t = 0; t < 4; ++t) acc[t] = (f32x4){0.f, 0.f, 0.f, 0.f};

#pragma unroll
    for (int kk = 0; kk < 2; ++kk) {
      const int cb = quad + 4 * kk;   // logical hi chunk
      bf16x8 a_hi = *(const bf16x8*)&eN[rowA * 64 + ((cb) ^ lr) * 4];
      bf16x8 a_lo = *(const bf16x8*)&eN[rowA * 64 + ((cb + 8) ^ lr) * 4];
#pragma unroll
      for (int t = 0; t < 4; ++t) {
        int rowB = cg * 64 + t * 16 + lr;
        bf16x8 b_hi = *(const bf16x8*)&eM[rowB * 64 + ((cb) ^ lr) * 4];
        bf16x8 b_lo = *(const bf16x8*)&eM[rowB * 64 + ((cb + 8) ^ lr) * 4];
        acc[t] = __builtin_amdgcn_mfma_f32_16x16x32_bf16(a_hi, b_hi, acc[t], 0, 0, 0);
        acc[t] = __builtin_amdgcn_mfma_f32_16x16x32_bf16(a_hi, b_lo, acc[t], 0, 0, 0);
        acc[t] = __builtin_amdgcn_mfma_f32_16x16x32_bf16(a_lo, b_hi, acc[t], 0, 0, 0);
      }
    }
    // pack d2 (f32) into d2f (C layout: col=lane&15, row=quad*4+reg)
#pragma unroll
    for (int t = 0; t < 4; ++t) {
#pragma unroll
      for (int reg = 0; reg < 4; ++reg) {
        int row = rt * 16 + quad * 4 + reg;
        int col = cg * 64 + t * 16 + lr;
        float d2 = fmaxf(sqA[n0 + row] + sqA[m0 + col] - 2.f * acc[t][reg], 0.f);
        d2f[row * 129 + col] = d2;
      }
    }
    __syncthreads();  // B2: d2f ready

    // drain: ALL 512 threads; register-resident sorted top-24, threshold pre-filter
#pragma unroll 1
    for (int j = 0; j < 16; ++j) {
      float v = d2f[dr * 129 + mb + j];
      if (v <= 100.f) {  // exact: rank metric == filter metric
        unsigned long long p =
            ((unsigned long long)__float_as_uint(v) << 32) | (unsigned)(m0 + mb + j);
        if (p < lst[23]) {
          lst[23] = p;
#pragma unroll
          for (int t = 23; t >= 1; --t) {
            unsigned long long a = lst[t - 1], bb = lst[t];
            bool sw = bb < a;
            lst[t - 1] = sw ? bb : a;
            lst[t] = sw ? a : bb;
          }
        }
      }
    }
    // next B1 orders this drain's d2f reads vs next chunk's d2f writes
  }
  __syncthreads();  // all drains done; tile memory dead -> reuse as dump

#pragma unroll
  for (int i = 0; i < 24; ++i) dump[((seg << 6) | dr) * 24 + i] = lst[i];
  __syncthreads();

  if (tid < 64) {
    const int r = tid;
    const int n = n0 + r;
    int pp[8] = {0, 0, 0, 0, 0, 0, 0, 0};
    unsigned long long h[8];
#pragma unroll
    for (int t = 0; t < 8; ++t) h[t] = dump[((t << 6) | r) * 24];
    int cnt = 0;
    const int base = (b * NB + n) * KNN;
    for (int k = 0; k < 24; ++k) {
      int bs = 0;
      unsigned long long mv = h[0];
#pragma unroll
      for (int t = 1; t < 8; ++t)
        if (h[t] < mv) { mv = h[t]; bs = t; }
      if ((unsigned)(mv >> 32) > 0x42C80000u) break;  // sentinel (pre-filtered lists)
      int mi = (int)(mv & 0xFFFFFFFFu);
      row_idx[base + cnt] = mi;
      atomicAdd(&col_cnt[b * NB + mi], 1);
      ++cnt;
      int np = ++pp[bs];
      h[bs] = (np < 24) ? dump[((bs << 6) | r) * 24 + np] : ~0ULL;
    }
    row_cnt[b * NB + n] = cnt;
#pragma unroll 4
    for (int j = cnt; j < 24; ++j) row_idx[base + j] = n;  // pad with self (valid gather idx)
  }
}

// ---------------- K4: exclusive scan of col_cnt (16384 entries), 1 block
__global__ __launch_bounds__(256) void k_scan(const int* __restrict__ col_cnt,
                                              int* __restrict__ col_start,
                                              int* __restrict__ col_cursor) {
  __shared__ int part[256];
  const int tid = threadIdx.x;
  const int base = tid * 64;
  int s = 0;
  for (int j = 0; j < 64; ++j) s += col_cnt[base + j];
  part[tid] = s;
  __syncthreads();
  for (int off = 1; off < 256; off <<= 1) {
    int v = (tid >= off) ? part[tid - off] : 0;
    __syncthreads();
    part[tid] += v;
    __syncthreads();
  }
  int run = part[tid] - s;
  for (int j = 0; j < 64; ++j) {
    col_start[base + j] = run;
    col_cursor[base + j] = run;
    run += col_cnt[base + j];
  }
}

// ---------------- K5: fill CSC column lists
__global__ __launch_bounds__(256) void k_fill(const int* __restrict__ row_idx,
                                              const int* __restrict__ row_cnt,
                                              int* __restrict__ col_cursor,
                                              int* __restrict__ col_list) {
  const int row = blockIdx.x * 256 + threadIdx.x;
  const int b = row >> 12;
  const int cnt = row_cnt[row];
  for (int j = 0; j < cnt; ++j) {
    int m = row_idx[row * KNN + j];
    int pos = atomicAdd(&col_cursor[(b << 12) + m], 1);
    col_list[pos] = row & 4095;
  }
}

// ---------------- K6: Yd[e,c] = (sum_{m in col(e)} X_lin[m,c]) / De[e]
__global__ __launch_bounds__(256) void k_yd(const float* __restrict__ xlin,
                                            const int* __restrict__ col_cnt,
                                            const int* __restrict__ col_start,
                                            const int* __restrict__ col_list,
                                            float* __restrict__ yd) {
  const int le = threadIdx.x >> 6;
  const int c4 = threadIdx.x & 63;
  const int be = blockIdx.x * 4 + le;
  const int b = be >> 12;
  const int deg = col_cnt[be];
  const int start = col_start[be];
  float4 acc = make_float4(0.f, 0.f, 0.f, 0.f);
  int j = 0;
  for (; j + 3 < deg; j += 4) {
    int ma = col_list[start + j], mb2 = col_list[start + j + 1];
    int mc = col_list[start + j + 2], md = col_list[start + j + 3];
    float4 va = *(const float4*)&xlin[(((size_t)(b << 12) + ma) << 8) + c4 * 4];
    float4 vb = *(const float4*)&xlin[(((size_t)(b << 12) + mb2) << 8) + c4 * 4];
    float4 vc = *(const float4*)&xlin[(((size_t)(b << 12) + mc) << 8) + c4 * 4];
    float4 vd = *(const float4*)&xlin[(((size_t)(b << 12) + md) << 8) + c4 * 4];
    acc.x += (va.x + vb.x) + (vc.x + vd.x);
    acc.y += (va.y + vb.y) + (vc.y + vd.y);
    acc.z += (va.z + vb.z) + (vc.z + vd.z);
    acc.w += (va.w + vb.w) + (vc.w + vd.w);
  }
  for (; j < deg; ++j) {
    int m = col_list[start + j];
    float4 v = *(const float4*)&xlin[(((size_t)(b << 12) + m) << 8) + c4 * 4];
    acc.x += v.x; acc.y += v.y; acc.z += v.z; acc.w += v.w;
  }
  float inv = 1.f / (float)deg;
  acc.x *= inv; acc.y *= inv; acc.z *= inv; acc.w *= inv;
  *(float4*)&yd[((size_t)be << 8) + c4 * 4] = acc;
}

// ---------------- K7: g[n,c] = (sum_{e in row(n)} Yd[e,c]) / Dv[n]
__global__ __launch_bounds__(256) void k_out2(const float* __restrict__ yd,
                                              const int* __restrict__ row_idx,
                                              const int* __restrict__ row_cnt,
                                              float* __restrict__ outf) {
  const int b = blockIdx.x >> 8;
  const int nt = blockIdx.x & 255;
  const int le = threadIdx.x >> 6;
  const int c4 = threadIdx.x & 63;
  for (int ii = 0; ii < 4; ++ii) {
    int n = nt * 16 + le * 4 + ii;
    int row = (b << 12) + n;
    int cnt = row_cnt[row];
    int idx[24];
    const int4* ip = (const int4*)(row_idx + (size_t)row * KNN);
#pragma unroll
    for (int t = 0; t < 6; ++t) {
      int4 v = ip[t];
      idx[4 * t] = v.x; idx[4 * t + 1] = v.y; idx[4 * t + 2] = v.z; idx[4 * t + 3] = v.w;
    }
    float4 acc = make_float4(0.f, 0.f, 0.f, 0.f);
#pragma unroll
    for (int j = 0; j < 24; ++j) {
      float wgt = (j < cnt) ? 1.f : 0.f;
      float4 v = *(const float4*)&yd[(((size_t)(b << 12) + idx[j]) << 8) + c4 * 4];
      acc.x = fmaf(wgt, v.x, acc.x);
      acc.y = fmaf(wgt, v.y, acc.y);
      acc.z = fmaf(wgt, v.z, acc.z);
      acc.w = fmaf(wgt, v.w, acc.w);
    }
    float inv = 1.f / (float)cnt;
    acc.x *= inv; acc.y *= inv; acc.z *= inv; acc.w *= inv;
    *(float4*)&outf[((size_t)row << 8) + c4 * 4] = acc;
  }
}

// ---------------- K8: outf += x (residual, via LDS transpose); accumulate BN sums
__global__ __launch_bounds__(256) void k_res_bn(const float* __restrict__ x,
                                                float* __restrict__ outf,
                                                float* __restrict__ bn_sum,
                                                float* __restrict__ bn_sumsq) {
  __shared__ float xt[256 * 69];
  const int b = blockIdx.x >> 6;
  const int n0 = (blockIdx.x & 63) << 6;
  const int tid = threadIdx.x;
#pragma unroll 4
  for (int k = 0; k < 16; ++k) {
    int q = tid + 256 * k;
    int c = q >> 4, f = q & 15;
    float4 v = *(const float4*)&x[((size_t)(b * CD + c)) * NB + n0 + 4 * f];
    xt[c * 69 + 4 * f + 0] = v.x;
    xt[c * 69 + 4 * f + 1] = v.y;
    xt[c * 69 + 4 * f + 2] = v.z;
    xt[c * 69 + 4 * f + 3] = v.w;
  }
  __syncthreads();
  float s = 0.f, q = 0.f;
  const size_t rbase = ((size_t)((b << 12) + n0)) << 8;
#pragma unroll 4
  for (int i = 0; i < 64; ++i) {
    float v = outf[rbase + (size_t)i * 256 + tid] + xt[tid * 69 + i];
    outf[rbase + (size_t)i * 256 + tid] = v;
    s += v;
    q = fmaf(v, v, q);
  }
  atomicAdd(&bn_sum[tid], s);
  atomicAdd(&bn_sumsq[tid], q);
}

// ---------------- K9: BN scale/shift per channel
__global__ __launch_bounds__(256) void k_bn(const float* __restrict__ bn_sum,
                                            const float* __restrict__ bn_sumsq,
                                            const float* __restrict__ gamma,
                                            const float* __restrict__ beta,
                                            float* __restrict__ scale,
                                            float* __restrict__ shift) {
  const int c = threadIdx.x;
  const float inv = 1.f / 16384.f;
  float mean = bn_sum[c] * inv;
  float var = bn_sumsq[c] * inv - mean * mean;
  float sc = gamma[c] * rsqrtf(var + 1e-5f);
  scale[c] = sc;
  shift[c] = beta[c] - mean * sc;
}

// ---------------- K10: normalize + SiLU + transpose to [B,C,N]
__global__ __launch_bounds__(256) void k_write(const float* __restrict__ outf,
                                               const float* __restrict__ scale,
                                               const float* __restrict__ shift,
                                               float* __restrict__ out) {
  __shared__ float tile[64 * 257];
  __shared__ float sc[256], sh[256];
  const int b = blockIdx.x >> 6;
  const int n0 = (blockIdx.x & 63) << 6;
  const int tid = threadIdx.x;
  sc[tid] = scale[tid];
  sh[tid] = shift[tid];
  __syncthreads();
#pragma unroll 4
  for (int i = 0; i < 64; ++i) {
    int idx = tid + 256 * i;
    int n = idx >> 8, c = idx & 255;
    float v = outf[(((size_t)(b << 12) + n0 + n) << 8) + c];
    v = fmaf(v, sc[c], sh[c]);
    float w = v / (1.f + expf(-v));  // SiLU
    tile[n * 257 + c] = w;
  }
  __syncthreads();
  const int nl = tid & 63;
  const int cg = tid >> 6;
#pragma unroll 4
  for (int j = 0; j < 64; ++j) {
    int c = cg * 64 + j;
    out[((size_t)(b * CD + c)) * NB + n0 + nl] = tile[nl * 257 + c];
  }
}

extern "C" void kernel_launch(void* const* d_in, const int* in_sizes, int n_in,
                              void* d_out, int out_size, void* d_ws, size_t ws_size,
                              hipStream_t stream) {
  const float* x      = (const float*)d_in[0];
  const float* fc_w   = (const float*)d_in[1];
  const float* fc_b   = (const float*)d_in[2];
  const float* dist_w = (const float*)d_in[3];
  const float* gamma  = (const float*)d_in[4];
  const float* beta   = (const float*)d_in[5];
  float* out = (float*)d_out;
  char* ws = (char*)d_ws;

  const size_t OFF_EHL   = 0;                   // 4 MB (16384 rows x 256 B)
  const size_t OFF_XLIN  = (size_t)4 << 20;
  const size_t OFF_YD    = (size_t)20 << 20;
  const size_t OFF_OUTF  = (size_t)36 << 20;
  const size_t OFF_SQ    = (size_t)52 << 20;
  const size_t OFF_RIDX  = OFF_SQ + 65536;
  const size_t OFF_RCNT  = OFF_RIDX + 1572864;
  const size_t OFF_CCNT  = OFF_RCNT + 65536;
  const size_t OFF_CSTART = OFF_CCNT + 65536;
  const size_t OFF_CCUR  = OFF_CSTART + 65536;
  const size_t OFF_CLIST = OFF_CCUR + 65536;
  const size_t OFF_BNS   = OFF_CLIST + 1572864;
  const size_t OFF_BNQ   = OFF_BNS + 1024;
  const size_t OFF_SCALE = OFF_BNQ + 1024;
  const size_t OFF_SHIFT = OFF_SCALE + 1024;
  const size_t TOTAL = OFF_SHIFT + 1024;
  if (ws_size < TOTAL) return;

  unsigned* emb_hl = (unsigned*)(ws + OFF_EHL);
  float* xlin  = (float*)(ws + OFF_XLIN);
  float* yd    = (float*)(ws + OFF_YD);
  float* outf  = (float*)(ws + OFF_OUTF);
  float* sq    = (float*)(ws + OFF_SQ);
  int* row_idx = (int*)(ws + OFF_RIDX);
  int* row_cnt = (int*)(ws + OFF_RCNT);
  int* col_cnt = (int*)(ws + OFF_CCNT);
  int* col_start = (int*)(ws + OFF_CSTART);
  int* col_cursor = (int*)(ws + OFF_CCUR);
  int* col_list = (int*)(ws + OFF_CLIST);
  float* bn_sum = (float*)(ws + OFF_BNS);
  float* bn_sumsq = (float*)(ws + OFF_BNQ);
  float* scale = (float*)(ws + OFF_SCALE);
  float* shift = (float*)(ws + OFF_SHIFT);

  hipMemsetAsync(col_cnt, 0, 65536, stream);
  hipMemsetAsync(bn_sum, 0, 2048, stream);

  k_emb<<<256, 256, 0, stream>>>(x, dist_w, emb_hl, sq);
  k_xlin<<<256, 256, 0, stream>>>(x, fc_w, fc_b, xlin);
  k_dist<<<256, 512, 0, stream>>>(emb_hl, sq, row_idx, row_cnt, col_cnt);
  k_scan<<<1, 256, 0, stream>>>(col_cnt, col_start, col_cursor);
  k_fill<<<64, 256, 0, stream>>>(row_idx, row_cnt, col_cursor, col_list);
  k_yd<<<4096, 256, 0, stream>>>(xlin, col_cnt, col_start, col_list, yd);
  k_out2<<<1024, 256, 0, stream>>>(yd, row_idx, row_cnt, outf);
  k_res_bn<<<256, 256, 0, stream>>>(x, outf, bn_sum, bn_sumsq);
  k_bn<<<1, 256, 0, stream>>>(bn_sum, bn_sumsq, gamma, beta, scale, shift);
  k_write<<<256, 256, 0, stream>>>(outf, scale, shift, out);
}

// Round 6
// 742.298 us; speedup vs baseline: 1.6853x; 1.6853x over previous
//
#include <hip/hip_runtime.h>

#define NB 4096      // N = H*W
#define BATCH 4
#define CD 256       // channels
#define ED 64        // embedding dim
#define KNN 24

typedef __attribute__((ext_vector_type(8))) short bf16x8;
typedef __attribute__((ext_vector_type(4))) float f32x4;

__device__ __forceinline__ unsigned short f2bf(float x) {
  unsigned u = __float_as_uint(x);
  unsigned r = (u + 0x7fffu + ((u >> 16) & 1u)) >> 16;
  return (unsigned short)r;
}

// ---------------- K1: emb = x @ dist_w^T  -> emb_hl (bf16 hi/lo, XOR-swizzled chunks) + sq (fp32)
__global__ __launch_bounds__(256) void k_emb(const float* __restrict__ x,
                                             const float* __restrict__ dist_w,
                                             unsigned* __restrict__ emb_hl,
                                             float* __restrict__ sq) {
  __shared__ float wds[ED * CD];   // 64 KB
  __shared__ float red[64 * 4];
  const int b = blockIdx.x >> 6;
  const int n0 = (blockIdx.x & 63) << 6;
  const int tid = threadIdx.x;
  const float4* wsrc = (const float4*)dist_w;
  float4* wdst = (float4*)wds;
#pragma unroll
  for (int k = 0; k < 16; ++k) wdst[tid + 256 * k] = wsrc[tid + 256 * k];
  __syncthreads();
  const int eg = tid >> 6;   // 0..3
  const int nl = tid & 63;
  const int n = n0 + nl;
  float acc[16];
#pragma unroll
  for (int t = 0; t < 16; ++t) acc[t] = 0.f;
  const float* xb = x + (size_t)b * CD * NB + n;
#pragma unroll 4
  for (int c = 0; c < CD; ++c) {
    float xv = xb[(size_t)c * NB];
#pragma unroll
    for (int t = 0; t < 16; ++t)
      acc[t] = fmaf(xv, wds[(eg * 16 + t) * CD + c], acc[t]);
  }
  float s = 0.f;
#pragma unroll
  for (int t = 0; t < 16; ++t) s = fmaf(acc[t], acc[t], s);
  unsigned hw[8], lw[8];
#pragma unroll
  for (int i = 0; i < 8; ++i) {
    unsigned short h0 = f2bf(acc[2 * i]);
    unsigned short h1 = f2bf(acc[2 * i + 1]);
    float l0f = acc[2 * i] - __uint_as_float((unsigned)h0 << 16);
    float l1f = acc[2 * i + 1] - __uint_as_float((unsigned)h1 << 16);
    hw[i] = (unsigned)h0 | ((unsigned)h1 << 16);
    lw[i] = (unsigned)f2bf(l0f) | ((unsigned)f2bf(l1f) << 16);
  }
  uint4* g = (uint4*)emb_hl;
  const size_t gb = ((size_t)(b * NB + n)) * 16;
  const int k15 = n & 15;
  g[gb + ((2 * eg) ^ k15)]     = make_uint4(hw[0], hw[1], hw[2], hw[3]);
  g[gb + ((2 * eg + 1) ^ k15)] = make_uint4(hw[4], hw[5], hw[6], hw[7]);
  g[gb + ((8 + 2 * eg) ^ k15)]     = make_uint4(lw[0], lw[1], lw[2], lw[3]);
  g[gb + ((8 + 2 * eg + 1) ^ k15)] = make_uint4(lw[4], lw[5], lw[6], lw[7]);
  red[nl * 4 + eg] = s;
  __syncthreads();
  if (tid < 64)
    sq[b * NB + n0 + tid] = red[tid * 4] + red[tid * 4 + 1] + red[tid * 4 + 2] + red[tid * 4 + 3];
}

// ---------------- K2: X_lin[b,n,c] = sum_k x[b,k,n]*fc_w[c,k] + fc_b[c]
__global__ __launch_bounds__(256) void k_xlin(const float* __restrict__ x,
                                              const float* __restrict__ fc_w,
                                              const float* __restrict__ fc_b,
                                              float* __restrict__ xlin) {
  __shared__ float xt[64 * 64];     // [k][n]
  __shared__ float wt[64 * 260];    // [k][c] padded
  const int b = blockIdx.x >> 6;
  const int n0 = (blockIdx.x & 63) << 6;
  const int tid = threadIdx.x;
  const int nl4 = tid & 15;
  const int cg = tid >> 4;
  float acc[4][16];
#pragma unroll
  for (int i = 0; i < 4; ++i)
#pragma unroll
    for (int j = 0; j < 16; ++j) acc[i][j] = 0.f;

  for (int kt = 0; kt < 4; ++kt) {
    __syncthreads();
#pragma unroll 4
    for (int i = 0; i < 16; ++i) {
      int idx = tid + 256 * i;
      int k = idx >> 6, n = idx & 63;
      xt[idx] = x[((size_t)(b * CD + kt * 64 + k)) * NB + n0 + n];
    }
#pragma unroll 4
    for (int i = 0; i < 16; ++i) {
      int q = tid + 256 * i;
      int c = q >> 4, k4 = (q & 15) * 4;
      float4 v = *(const float4*)&fc_w[(size_t)c * CD + kt * 64 + k4];
      wt[(k4 + 0) * 260 + c] = v.x;
      wt[(k4 + 1) * 260 + c] = v.y;
      wt[(k4 + 2) * 260 + c] = v.z;
      wt[(k4 + 3) * 260 + c] = v.w;
    }
    __syncthreads();
#pragma unroll 2
    for (int k = 0; k < 64; ++k) {
      float4 xv = *(const float4*)&xt[k * 64 + 4 * nl4];
#pragma unroll
      for (int j = 0; j < 4; ++j) {
        float4 wv = *(const float4*)&wt[k * 260 + 4 * cg + 64 * j];
        const float* wp = &wv.x;
#pragma unroll
        for (int l = 0; l < 4; ++l) {
          acc[0][4 * j + l] = fmaf(xv.x, wp[l], acc[0][4 * j + l]);
          acc[1][4 * j + l] = fmaf(xv.y, wp[l], acc[1][4 * j + l]);
          acc[2][4 * j + l] = fmaf(xv.z, wp[l], acc[2][4 * j + l]);
          acc[3][4 * j + l] = fmaf(xv.w, wp[l], acc[3][4 * j + l]);
        }
      }
    }
  }
#pragma unroll
  for (int i = 0; i < 4; ++i) {
    int n = n0 + 4 * nl4 + i;
    float* dst = xlin + ((size_t)(b * NB + n)) * CD;
#pragma unroll
    for (int j = 0; j < 4; ++j) {
      int c = 4 * cg + 64 * j;
      float4 bv = *(const float4*)&fc_b[c];
      float4 o;
      o.x = acc[i][4 * j + 0] + bv.x;
      o.y = acc[i][4 * j + 1] + bv.y;
      o.z = acc[i][4 * j + 2] + bv.z;
      o.w = acc[i][4 * j + 3] + bv.w;
      *(float4*)&dst[c] = o;
    }
  }
}

// ---------------- K3 v6: m-split partial kNN. Block = 64 rows x 512 m (8 chunks of 64).
// grid 2048 (b,ntile,mpart). Register top-24 per (row,seg); 4-way merge -> sorted partial to global.
__global__ __launch_bounds__(512) void k_distp(const unsigned* __restrict__ emb_hl,
                                               const float* __restrict__ sq,
                                               unsigned long long* __restrict__ part) {
  __shared__ __align__(16) unsigned char smem[51712];
  unsigned* eN = (unsigned*)smem;                        // 16384 B
  unsigned* eM = (unsigned*)(smem + 16384);              // 16384 B
  float* d2f   = (float*)(smem + 32768);                 // 16640 B (64 x 65)
  float* sqN   = (float*)(smem + 49408);                 // 256 B
  float* sqMp  = (float*)(smem + 49664);                 // 2048 B (512 m of this part)
  unsigned long long* dump = (unsigned long long*)smem;  // overlay phase 2: 49152 B (4x64x24)

  const int bid = blockIdx.x;
  const int mp = bid & 7;
  const int nt = (bid >> 3) & 63;
  const int b  = bid >> 9;
  const int n0 = nt << 6;
  const int m00 = mp << 9;   // global m base of this part
  const int tid = threadIdx.x;
  const uint4* embg = (const uint4*)emb_hl;
  const size_t bbase = (size_t)b * NB;

  // stage eN + sq slices (B1 of first chunk orders these vs use)
#pragma unroll
  for (int k = 0; k < 2; ++k) {
    int q = tid + 512 * k;
    int r = q >> 4, ch = q & 15;
    *(uint4*)&eN[r * 64 + ch * 4] = embg[(bbase + n0 + r) * 16 + ch];
  }
  if (tid < 64) sqN[tid] = sq[b * NB + n0 + tid];
  sqMp[tid] = sq[b * NB + m00 + tid];

  const int w = tid >> 6, lane = tid & 63;
  const int quad = lane >> 4, lr = lane & 15;
  const int rt = w >> 1;            // row tile 0..3
  const int ct0 = (w & 1) * 2;      // first of my 2 col tiles (of 4)
  const int rowA = rt * 16 + lr;

  const int seg = tid >> 6;         // 0..7; only seg<4 drain (16 cols each)
  const int dr = tid & 63;

  unsigned long long lst[24];
#pragma unroll
  for (int i = 0; i < 24; ++i) lst[i] = ~0ULL;

  for (int ci = 0; ci < 8; ++ci) {
    const int m0 = ci << 6;  // local m offset
#pragma unroll
    for (int k = 0; k < 2; ++k) {
      int q = tid + 512 * k;
      int r = q >> 4, ch = q & 15;
      *(uint4*)&eM[r * 64 + ch * 4] = embg[(bbase + m00 + m0 + r) * 16 + ch];
    }
    __syncthreads();  // B1: eM ready AND previous drain done

    f32x4 acc0 = {0.f, 0.f, 0.f, 0.f};
    f32x4 acc1 = {0.f, 0.f, 0.f, 0.f};
#pragma unroll
    for (int kk = 0; kk < 2; ++kk) {
      const int cb = quad + 4 * kk;
      bf16x8 a_hi = *(const bf16x8*)&eN[rowA * 64 + ((cb) ^ lr) * 4];
      bf16x8 a_lo = *(const bf16x8*)&eN[rowA * 64 + ((cb + 8) ^ lr) * 4];
      int rowB0 = ct0 * 16 + lr, rowB1 = rowB0 + 16;
      bf16x8 b0_hi = *(const bf16x8*)&eM[rowB0 * 64 + ((cb) ^ lr) * 4];
      bf16x8 b0_lo = *(const bf16x8*)&eM[rowB0 * 64 + ((cb + 8) ^ lr) * 4];
      bf16x8 b1_hi = *(const bf16x8*)&eM[rowB1 * 64 + ((cb) ^ lr) * 4];
      bf16x8 b1_lo = *(const bf16x8*)&eM[rowB1 * 64 + ((cb + 8) ^ lr) * 4];
      acc0 = __builtin_amdgcn_mfma_f32_16x16x32_bf16(a_hi, b0_hi, acc0, 0, 0, 0);
      acc0 = __builtin_amdgcn_mfma_f32_16x16x32_bf16(a_hi, b0_lo, acc0, 0, 0, 0);
      acc0 = __builtin_amdgcn_mfma_f32_16x16x32_bf16(a_lo, b0_hi, acc0, 0, 0, 0);
      acc1 = __builtin_amdgcn_mfma_f32_16x16x32_bf16(a_hi, b1_hi, acc1, 0, 0, 0);
      acc1 = __builtin_amdgcn_mfma_f32_16x16x32_bf16(a_hi, b1_lo, acc1, 0, 0, 0);
      acc1 = __builtin_amdgcn_mfma_f32_16x16x32_bf16(a_lo, b1_hi, acc1, 0, 0, 0);
    }
#pragma unroll
    for (int reg = 0; reg < 4; ++reg) {
      int row = rt * 16 + quad * 4 + reg;
      int c0 = ct0 * 16 + lr, c1 = c0 + 16;
      float d20 = fmaxf(sqN[row] + sqMp[m0 + c0] - 2.f * acc0[reg], 0.f);
      float d21 = fmaxf(sqN[row] + sqMp[m0 + c1] - 2.f * acc1[reg], 0.f);
      d2f[row * 65 + c0] = d20;
      d2f[row * 65 + c1] = d21;
    }
    __syncthreads();  // B2: d2f ready (also: frag reads done -> eM restage safe)

    if (seg < 4) {
#pragma unroll 1
      for (int j = 0; j < 16; ++j) {
        float v = d2f[dr * 65 + seg * 16 + j];
        if (v <= 100.f) {  // exact pre-filter (rank metric == filter metric)
          unsigned long long p =
              ((unsigned long long)__float_as_uint(v) << 32) | (unsigned)(m00 + m0 + seg * 16 + j);
          if (p < lst[23]) {
            lst[23] = p;
#pragma unroll
            for (int t = 23; t >= 1; --t) {
              unsigned long long a = lst[t - 1], bb = lst[t];
              bool sw = bb < a;
              lst[t - 1] = sw ? bb : a;
              lst[t] = sw ? a : bb;
            }
          }
        }
      }
    }
    // seg>=4 waves run ahead to stage next eM; B1 orders drain reads vs d2f overwrite
  }
  __syncthreads();  // tiles dead -> reuse as dump

  if (seg < 4) {
#pragma unroll
    for (int i = 0; i < 24; ++i) dump[((seg << 6) | dr) * 24 + i] = lst[i];
  }
  __syncthreads();

  if (tid < 64) {
    int pp[4] = {0, 0, 0, 0};
    unsigned long long h[4];
#pragma unroll
    for (int t = 0; t < 4; ++t) h[t] = dump[((t << 6) | tid) * 24];
    unsigned long long* op = part + ((size_t)bid * 64 + tid) * 24;
#pragma unroll 1
    for (int k = 0; k < 24; ++k) {
      int bs = 0;
      unsigned long long mv = h[0];
#pragma unroll
      for (int t = 1; t < 4; ++t)
        if (h[t] < mv) { mv = h[t]; bs = t; }
      op[k] = mv;  // sentinels ok; k_merge cuts
      int np = ++pp[bs];
      h[bs] = (np < 24) ? dump[((bs << 6) | tid) * 24 + np] : ~0ULL;
    }
  }
}

// ---------------- K3b: merge 8 sorted partials per row -> row_idx/row_cnt/col_cnt
__global__ __launch_bounds__(256) void k_merge(const unsigned long long* __restrict__ part,
                                               int* __restrict__ row_idx,
                                               int* __restrict__ row_cnt,
                                               int* __restrict__ col_cnt) {
  const int row = blockIdx.x * 256 + threadIdx.x;  // b*4096 + n
  const int b = row >> 12;
  const int n = row & 4095;
  const int nt = n >> 6, r = n & 63;
  const size_t gb = (size_t)(((b << 6) | nt) << 3);  // block base (b,nt,mp=0)
  unsigned long long h[8];
  int pp[8];
#pragma unroll
  for (int t = 0; t < 8; ++t) {
    h[t] = part[((gb + t) * 64 + r) * 24];
    pp[t] = 0;
  }
  int cnt = 0;
  const int base = row * KNN;
  for (int k = 0; k < 24; ++k) {
    int bs = 0;
    unsigned long long mv = h[0];
#pragma unroll
    for (int t = 1; t < 8; ++t)
      if (h[t] < mv) { mv = h[t]; bs = t; }
    if ((unsigned)(mv >> 32) > 0x42C80000u) break;  // sentinel / beyond threshold
    int mi = (int)(mv & 0xFFFFFFFFu);
    row_idx[base + cnt] = mi;
    atomicAdd(&col_cnt[(b << 12) + mi], 1);
    ++cnt;
    int np = ++pp[bs];
    h[bs] = (np < 24) ? part[((gb + bs) * 64 + r) * 24 + np] : ~0ULL;
  }
  row_cnt[row] = cnt;
#pragma unroll 4
  for (int j = cnt; j < 24; ++j) row_idx[base + j] = n;  // pad with self (valid gather idx)
}

// ---------------- K4: exclusive scan of col_cnt (16384 entries), 1 block
__global__ __launch_bounds__(256) void k_scan(const int* __restrict__ col_cnt,
                                              int* __restrict__ col_start,
                                              int* __restrict__ col_cursor) {
  __shared__ int part[256];
  const int tid = threadIdx.x;
  const int base = tid * 64;
  int s = 0;
  for (int j = 0; j < 64; ++j) s += col_cnt[base + j];
  part[tid] = s;
  __syncthreads();
  for (int off = 1; off < 256; off <<= 1) {
    int v = (tid >= off) ? part[tid - off] : 0;
    __syncthreads();
    part[tid] += v;
    __syncthreads();
  }
  int run = part[tid] - s;
  for (int j = 0; j < 64; ++j) {
    col_start[base + j] = run;
    col_cursor[base + j] = run;
    run += col_cnt[base + j];
  }
}

// ---------------- K5: fill CSC column lists
__global__ __launch_bounds__(256) void k_fill(const int* __restrict__ row_idx,
                                              const int* __restrict__ row_cnt,
                                              int* __restrict__ col_cursor,
                                              int* __restrict__ col_list) {
  const int row = blockIdx.x * 256 + threadIdx.x;
  const int b = row >> 12;
  const int cnt = row_cnt[row];
  for (int j = 0; j < cnt; ++j) {
    int m = row_idx[row * KNN + j];
    int pos = atomicAdd(&col_cursor[(b << 12) + m], 1);
    col_list[pos] = row & 4095;
  }
}

// ---------------- K6: Yd[e,c] = (sum_{m in col(e)} X_lin[m,c]) / De[e]
__global__ __launch_bounds__(256) void k_yd(const float* __restrict__ xlin,
                                            const int* __restrict__ col_cnt,
                                            const int* __restrict__ col_start,
                                            const int* __restrict__ col_list,
                                            float* __restrict__ yd) {
  const int le = threadIdx.x >> 6;
  const int c4 = threadIdx.x & 63;
  const int be = blockIdx.x * 4 + le;
  const int b = be >> 12;
  const int deg = col_cnt[be];
  const int start = col_start[be];
  float4 acc = make_float4(0.f, 0.f, 0.f, 0.f);
  int j = 0;
  for (; j + 3 < deg; j += 4) {
    int ma = col_list[start + j], mb2 = col_list[start + j + 1];
    int mc = col_list[start + j + 2], md = col_list[start + j + 3];
    float4 va = *(const float4*)&xlin[(((size_t)(b << 12) + ma) << 8) + c4 * 4];
    float4 vb = *(const float4*)&xlin[(((size_t)(b << 12) + mb2) << 8) + c4 * 4];
    float4 vc = *(const float4*)&xlin[(((size_t)(b << 12) + mc) << 8) + c4 * 4];
    float4 vd = *(const float4*)&xlin[(((size_t)(b << 12) + md) << 8) + c4 * 4];
    acc.x += (va.x + vb.x) + (vc.x + vd.x);
    acc.y += (va.y + vb.y) + (vc.y + vd.y);
    acc.z += (va.z + vb.z) + (vc.z + vd.z);
    acc.w += (va.w + vb.w) + (vc.w + vd.w);
  }
  for (; j < deg; ++j) {
    int m = col_list[start + j];
    float4 v = *(const float4*)&xlin[(((size_t)(b << 12) + m) << 8) + c4 * 4];
    acc.x += v.x; acc.y += v.y; acc.z += v.z; acc.w += v.w;
  }
  float inv = 1.f / (float)deg;
  acc.x *= inv; acc.y *= inv; acc.z *= inv; acc.w *= inv;
  *(float4*)&yd[((size_t)be << 8) + c4 * 4] = acc;
}

// ---------------- K7: g[n,c] = (sum_{e in row(n)} Yd[e,c]) / Dv[n]
__global__ __launch_bounds__(256) void k_out2(const float* __restrict__ yd,
                                              const int* __restrict__ row_idx,
                                              const int* __restrict__ row_cnt,
                                              float* __restrict__ outf) {
  const int b = blockIdx.x >> 8;
  const int nt = blockIdx.x & 255;
  const int le = threadIdx.x >> 6;
  const int c4 = threadIdx.x & 63;
  for (int ii = 0; ii < 4; ++ii) {
    int n = nt * 16 + le * 4 + ii;
    int row = (b << 12) + n;
    int cnt = row_cnt[row];
    int idx[24];
    const int4* ip = (const int4*)(row_idx + (size_t)row * KNN);
#pragma unroll
    for (int t = 0; t < 6; ++t) {
      int4 v = ip[t];
      idx[4 * t] = v.x; idx[4 * t + 1] = v.y; idx[4 * t + 2] = v.z; idx[4 * t + 3] = v.w;
    }
    float4 acc = make_float4(0.f, 0.f, 0.f, 0.f);
#pragma unroll
    for (int j = 0; j < 24; ++j) {
      float wgt = (j < cnt) ? 1.f : 0.f;
      float4 v = *(const float4*)&yd[(((size_t)(b << 12) + idx[j]) << 8) + c4 * 4];
      acc.x = fmaf(wgt, v.x, acc.x);
      acc.y = fmaf(wgt, v.y, acc.y);
      acc.z = fmaf(wgt, v.z, acc.z);
      acc.w = fmaf(wgt, v.w, acc.w);
    }
    float inv = 1.f / (float)cnt;
    acc.x *= inv; acc.y *= inv; acc.z *= inv; acc.w *= inv;
    *(float4*)&outf[((size_t)row << 8) + c4 * 4] = acc;
  }
}

// ---------------- K8: outf += x (residual, via LDS transpose); accumulate BN sums
__global__ __launch_bounds__(256) void k_res_bn(const float* __restrict__ x,
                                                float* __restrict__ outf,
                                                float* __restrict__ bn_sum,
                                                float* __restrict__ bn_sumsq) {
  __shared__ float xt[256 * 69];
  const int b = blockIdx.x >> 6;
  const int n0 = (blockIdx.x & 63) << 6;
  const int tid = threadIdx.x;
#pragma unroll 4
  for (int k = 0; k < 16; ++k) {
    int q = tid + 256 * k;
    int c = q >> 4, f = q & 15;
    float4 v = *(const float4*)&x[((size_t)(b * CD + c)) * NB + n0 + 4 * f];
    xt[c * 69 + 4 * f + 0] = v.x;
    xt[c * 69 + 4 * f + 1] = v.y;
    xt[c * 69 + 4 * f + 2] = v.z;
    xt[c * 69 + 4 * f + 3] = v.w;
  }
  __syncthreads();
  float s = 0.f, q = 0.f;
  const size_t rbase = ((size_t)((b << 12) + n0)) << 8;
#pragma unroll 4
  for (int i = 0; i < 64; ++i) {
    float v = outf[rbase + (size_t)i * 256 + tid] + xt[tid * 69 + i];
    outf[rbase + (size_t)i * 256 + tid] = v;
    s += v;
    q = fmaf(v, v, q);
  }
  atomicAdd(&bn_sum[tid], s);
  atomicAdd(&bn_sumsq[tid], q);
}

// ---------------- K9: BN scale/shift per channel
__global__ __launch_bounds__(256) void k_bn(const float* __restrict__ bn_sum,
                                            const float* __restrict__ bn_sumsq,
                                            const float* __restrict__ gamma,
                                            const float* __restrict__ beta,
                                            float* __restrict__ scale,
                                            float* __restrict__ shift) {
  const int c = threadIdx.x;
  const float inv = 1.f / 16384.f;
  float mean = bn_sum[c] * inv;
  float var = bn_sumsq[c] * inv - mean * mean;
  float sc = gamma[c] * rsqrtf(var + 1e-5f);
  scale[c] = sc;
  shift[c] = beta[c] - mean * sc;
}

// ---------------- K10: normalize + SiLU + transpose to [B,C,N]
__global__ __launch_bounds__(256) void k_write(const float* __restrict__ outf,
                                               const float* __restrict__ scale,
                                               const float* __restrict__ shift,
                                               float* __restrict__ out) {
  __shared__ float tile[64 * 257];
  __shared__ float sc[256], sh[256];
  const int b = blockIdx.x >> 6;
  const int n0 = (blockIdx.x & 63) << 6;
  const int tid = threadIdx.x;
  sc[tid] = scale[tid];
  sh[tid] = shift[tid];
  __syncthreads();
#pragma unroll 4
  for (int i = 0; i < 64; ++i) {
    int idx = tid + 256 * i;
    int n = idx >> 8, c = idx & 255;
    float v = outf[(((size_t)(b << 12) + n0 + n) << 8) + c];
    v = fmaf(v, sc[c], sh[c]);
    float w = v / (1.f + expf(-v));  // SiLU
    tile[n * 257 + c] = w;
  }
  __syncthreads();
  const int nl = tid & 63;
  const int cg = tid >> 6;
#pragma unroll 4
  for (int j = 0; j < 64; ++j) {
    int c = cg * 64 + j;
    out[((size_t)(b * CD + c)) * NB + n0 + nl] = tile[nl * 257 + c];
  }
}

extern "C" void kernel_launch(void* const* d_in, const int* in_sizes, int n_in,
                              void* d_out, int out_size, void* d_ws, size_t ws_size,
                              hipStream_t stream) {
  const float* x      = (const float*)d_in[0];
  const float* fc_w   = (const float*)d_in[1];
  const float* fc_b   = (const float*)d_in[2];
  const float* dist_w = (const float*)d_in[3];
  const float* gamma  = (const float*)d_in[4];
  const float* beta   = (const float*)d_in[5];
  float* out = (float*)d_out;
  char* ws = (char*)d_ws;

  const size_t OFF_EHL   = 0;                   // 4 MB
  const size_t OFF_XLIN  = (size_t)4 << 20;     // 16 MB
  const size_t OFF_YD    = (size_t)20 << 20;    // 16 MB (part buffer overlays yd+outf: both dead then)
  const size_t OFF_OUTF  = (size_t)36 << 20;    // 16 MB
  const size_t OFF_SQ    = (size_t)52 << 20;
  const size_t OFF_RIDX  = OFF_SQ + 65536;
  const size_t OFF_RCNT  = OFF_RIDX + 1572864;
  const size_t OFF_CCNT  = OFF_RCNT + 65536;
  const size_t OFF_CSTART = OFF_CCNT + 65536;
  const size_t OFF_CCUR  = OFF_CSTART + 65536;
  const size_t OFF_CLIST = OFF_CCUR + 65536;
  const size_t OFF_BNS   = OFF_CLIST + 1572864;
  const size_t OFF_BNQ   = OFF_BNS + 1024;
  const size_t OFF_SCALE = OFF_BNQ + 1024;
  const size_t OFF_SHIFT = OFF_SCALE + 1024;
  const size_t TOTAL = OFF_SHIFT + 1024;
  if (ws_size < TOTAL) return;

  unsigned* emb_hl = (unsigned*)(ws + OFF_EHL);
  float* xlin  = (float*)(ws + OFF_XLIN);
  float* yd    = (float*)(ws + OFF_YD);
  float* outf  = (float*)(ws + OFF_OUTF);
  unsigned long long* part = (unsigned long long*)(ws + OFF_YD);  // 25.2 MB overlay (yd+outf dead here)
  float* sq    = (float*)(ws + OFF_SQ);
  int* row_idx = (int*)(ws + OFF_RIDX);
  int* row_cnt = (int*)(ws + OFF_RCNT);
  int* col_cnt = (int*)(ws + OFF_CCNT);
  int* col_start = (int*)(ws + OFF_CSTART);
  int* col_cursor = (int*)(ws + OFF_CCUR);
  int* col_list = (int*)(ws + OFF_CLIST);
  float* bn_sum = (float*)(ws + OFF_BNS);
  float* bn_sumsq = (float*)(ws + OFF_BNQ);
  float* scale = (float*)(ws + OFF_SCALE);
  float* shift = (float*)(ws + OFF_SHIFT);

  hipMemsetAsync(col_cnt, 0, 65536, stream);
  hipMemsetAsync(bn_sum, 0, 2048, stream);

  k_emb<<<256, 256, 0, stream>>>(x, dist_w, emb_hl, sq);
  k_xlin<<<256, 256, 0, stream>>>(x, fc_w, fc_b, xlin);
  k_distp<<<2048, 512, 0, stream>>>(emb_hl, sq, part);
  k_merge<<<64, 256, 0, stream>>>(part, row_idx, row_cnt, col_cnt);
  k_scan<<<1, 256, 0, stream>>>(col_cnt, col_start, col_cursor);
  k_fill<<<64, 256, 0, stream>>>(row_idx, row_cnt, col_cursor, col_list);
  k_yd<<<4096, 256, 0, stream>>>(xlin, col_cnt, col_start, col_list, yd);
  k_out2<<<1024, 256, 0, stream>>>(yd, row_idx, row_cnt, outf);
  k_res_bn<<<256, 256, 0, stream>>>(x, outf, bn_sum, bn_sumsq);
  k_bn<<<1, 256, 0, stream>>>(bn_sum, bn_sumsq, gamma, beta, scale, shift);
  k_write<<<256, 256, 0, stream>>>(outf, scale, shift, out);
}

// Round 7
// 735.877 us; speedup vs baseline: 1.7001x; 1.0087x over previous
//
#include <hip/hip_runtime.h>

#define NB 4096      // N = H*W
#define BATCH 4
#define CD 256       // channels
#define ED 64        // embedding dim
#define KNN 24

typedef __attribute__((ext_vector_type(8))) short bf16x8;
typedef __attribute__((ext_vector_type(4))) float f32x4;

__device__ __forceinline__ unsigned short f2bf(float x) {
  unsigned u = __float_as_uint(x);
  unsigned r = (u + 0x7fffu + ((u >> 16) & 1u)) >> 16;
  return (unsigned short)r;
}

// ---------------- K1: emb = x @ dist_w^T  -> emb_hl (bf16 hi/lo, XOR-swizzled chunks) + sq (fp32)
__global__ __launch_bounds__(256) void k_emb(const float* __restrict__ x,
                                             const float* __restrict__ dist_w,
                                             unsigned* __restrict__ emb_hl,
                                             float* __restrict__ sq) {
  __shared__ float wds[ED * CD];   // 64 KB
  __shared__ float red[64 * 4];
  const int b = blockIdx.x >> 6;
  const int n0 = (blockIdx.x & 63) << 6;
  const int tid = threadIdx.x;
  const float4* wsrc = (const float4*)dist_w;
  float4* wdst = (float4*)wds;
#pragma unroll
  for (int k = 0; k < 16; ++k) wdst[tid + 256 * k] = wsrc[tid + 256 * k];
  __syncthreads();
  const int eg = tid >> 6;   // 0..3
  const int nl = tid & 63;
  const int n = n0 + nl;
  float acc[16];
#pragma unroll
  for (int t = 0; t < 16; ++t) acc[t] = 0.f;
  const float* xb = x + (size_t)b * CD * NB + n;
#pragma unroll 4
  for (int c = 0; c < CD; ++c) {
    float xv = xb[(size_t)c * NB];
#pragma unroll
    for (int t = 0; t < 16; ++t)
      acc[t] = fmaf(xv, wds[(eg * 16 + t) * CD + c], acc[t]);
  }
  float s = 0.f;
#pragma unroll
  for (int t = 0; t < 16; ++t) s = fmaf(acc[t], acc[t], s);
  unsigned hw[8], lw[8];
#pragma unroll
  for (int i = 0; i < 8; ++i) {
    unsigned short h0 = f2bf(acc[2 * i]);
    unsigned short h1 = f2bf(acc[2 * i + 1]);
    float l0f = acc[2 * i] - __uint_as_float((unsigned)h0 << 16);
    float l1f = acc[2 * i + 1] - __uint_as_float((unsigned)h1 << 16);
    hw[i] = (unsigned)h0 | ((unsigned)h1 << 16);
    lw[i] = (unsigned)f2bf(l0f) | ((unsigned)f2bf(l1f) << 16);
  }
  uint4* g = (uint4*)emb_hl;
  const size_t gb = ((size_t)(b * NB + n)) * 16;
  const int k15 = n & 15;
  g[gb + ((2 * eg) ^ k15)]     = make_uint4(hw[0], hw[1], hw[2], hw[3]);
  g[gb + ((2 * eg + 1) ^ k15)] = make_uint4(hw[4], hw[5], hw[6], hw[7]);
  g[gb + ((8 + 2 * eg) ^ k15)]     = make_uint4(lw[0], lw[1], lw[2], lw[3]);
  g[gb + ((8 + 2 * eg + 1) ^ k15)] = make_uint4(lw[4], lw[5], lw[6], lw[7]);
  red[nl * 4 + eg] = s;
  __syncthreads();
  if (tid < 64)
    sq[b * NB + n0 + tid] = red[tid * 4] + red[tid * 4 + 1] + red[tid * 4 + 2] + red[tid * 4 + 3];
}

// ---------------- K2: X_lin[b,n,c] = sum_k x[b,k,n]*fc_w[c,k] + fc_b[c]
__global__ __launch_bounds__(256) void k_xlin(const float* __restrict__ x,
                                              const float* __restrict__ fc_w,
                                              const float* __restrict__ fc_b,
                                              float* __restrict__ xlin) {
  __shared__ float xt[64 * 64];     // [k][n]
  __shared__ float wt[64 * 260];    // [k][c] padded
  const int b = blockIdx.x >> 6;
  const int n0 = (blockIdx.x & 63) << 6;
  const int tid = threadIdx.x;
  const int nl4 = tid & 15;
  const int cg = tid >> 4;
  float acc[4][16];
#pragma unroll
  for (int i = 0; i < 4; ++i)
#pragma unroll
    for (int j = 0; j < 16; ++j) acc[i][j] = 0.f;

  for (int kt = 0; kt < 4; ++kt) {
    __syncthreads();
#pragma unroll 4
    for (int i = 0; i < 16; ++i) {
      int idx = tid + 256 * i;
      int k = idx >> 6, n = idx & 63;
      xt[idx] = x[((size_t)(b * CD + kt * 64 + k)) * NB + n0 + n];
    }
#pragma unroll 4
    for (int i = 0; i < 16; ++i) {
      int q = tid + 256 * i;
      int c = q >> 4, k4 = (q & 15) * 4;
      float4 v = *(const float4*)&fc_w[(size_t)c * CD + kt * 64 + k4];
      wt[(k4 + 0) * 260 + c] = v.x;
      wt[(k4 + 1) * 260 + c] = v.y;
      wt[(k4 + 2) * 260 + c] = v.z;
      wt[(k4 + 3) * 260 + c] = v.w;
    }
    __syncthreads();
#pragma unroll 2
    for (int k = 0; k < 64; ++k) {
      float4 xv = *(const float4*)&xt[k * 64 + 4 * nl4];
#pragma unroll
      for (int j = 0; j < 4; ++j) {
        float4 wv = *(const float4*)&wt[k * 260 + 4 * cg + 64 * j];
        const float* wp = &wv.x;
#pragma unroll
        for (int l = 0; l < 4; ++l) {
          acc[0][4 * j + l] = fmaf(xv.x, wp[l], acc[0][4 * j + l]);
          acc[1][4 * j + l] = fmaf(xv.y, wp[l], acc[1][4 * j + l]);
          acc[2][4 * j + l] = fmaf(xv.z, wp[l], acc[2][4 * j + l]);
          acc[3][4 * j + l] = fmaf(xv.w, wp[l], acc[3][4 * j + l]);
        }
      }
    }
  }
#pragma unroll
  for (int i = 0; i < 4; ++i) {
    int n = n0 + 4 * nl4 + i;
    float* dst = xlin + ((size_t)(b * NB + n)) * CD;
#pragma unroll
    for (int j = 0; j < 4; ++j) {
      int c = 4 * cg + 64 * j;
      float4 bv = *(const float4*)&fc_b[c];
      float4 o;
      o.x = acc[i][4 * j + 0] + bv.x;
      o.y = acc[i][4 * j + 1] + bv.y;
      o.z = acc[i][4 * j + 2] + bv.z;
      o.w = acc[i][4 * j + 3] + bv.w;
      *(float4*)&dst[c] = o;
    }
  }
}

// ---------------- K3 v7: m-split partial kNN, register top-24 FORCED into VGPRs.
// __launch_bounds__(512,4): min 4 waves/EU -> 128-VGPR cap; lst[24] (48 VGPR) stays
// directly addressable (r6's 56-VGPR allocation pushed it to AGPR/scratch -> 64% VALUBusy
// of pure list-shuffling). 2 blocks/CU by LDS (51.7 KB).
__global__ __launch_bounds__(512, 4) void k_distp(const unsigned* __restrict__ emb_hl,
                                                  const float* __restrict__ sq,
                                                  unsigned long long* __restrict__ part) {
  __shared__ __align__(16) unsigned char smem[51712];
  unsigned* eN = (unsigned*)smem;                        // 16384 B
  unsigned* eM = (unsigned*)(smem + 16384);              // 16384 B
  float* d2f   = (float*)(smem + 32768);                 // 16640 B (64 x 65)
  float* sqN   = (float*)(smem + 49408);                 // 256 B
  float* sqMp  = (float*)(smem + 49664);                 // 2048 B (512 m of this part)
  unsigned long long* dump = (unsigned long long*)smem;  // overlay phase 2: 49152 B (4x64x24)

  const int bid = blockIdx.x;
  const int mp = bid & 7;
  const int nt = (bid >> 3) & 63;
  const int b  = bid >> 9;
  const int n0 = nt << 6;
  const int m00 = mp << 9;   // global m base of this part
  const int tid = threadIdx.x;
  const uint4* embg = (const uint4*)emb_hl;
  const size_t bbase = (size_t)b * NB;

  // stage eN + sq slices (B1 of first chunk orders these vs use)
#pragma unroll
  for (int k = 0; k < 2; ++k) {
    int q = tid + 512 * k;
    int r = q >> 4, ch = q & 15;
    *(uint4*)&eN[r * 64 + ch * 4] = embg[(bbase + n0 + r) * 16 + ch];
  }
  if (tid < 64) sqN[tid] = sq[b * NB + n0 + tid];
  sqMp[tid] = sq[b * NB + m00 + tid];

  const int w = tid >> 6, lane = tid & 63;
  const int quad = lane >> 4, lr = lane & 15;
  const int rt = w >> 1;            // row tile 0..3
  const int ct0 = (w & 1) * 2;      // first of my 2 col tiles (of 4)
  const int rowA = rt * 16 + lr;

  const int seg = tid >> 6;         // 0..7; only seg<4 drain (16 cols each)
  const int dr = tid & 63;

  unsigned long long lst[24];
#pragma unroll
  for (int i = 0; i < 24; ++i) lst[i] = ~0ULL;

  for (int ci = 0; ci < 8; ++ci) {
    const int m0 = ci << 6;  // local m offset
#pragma unroll
    for (int k = 0; k < 2; ++k) {
      int q = tid + 512 * k;
      int r = q >> 4, ch = q & 15;
      *(uint4*)&eM[r * 64 + ch * 4] = embg[(bbase + m00 + m0 + r) * 16 + ch];
    }
    __syncthreads();  // B1: eM ready AND previous drain done

    f32x4 acc0 = {0.f, 0.f, 0.f, 0.f};
    f32x4 acc1 = {0.f, 0.f, 0.f, 0.f};
#pragma unroll
    for (int kk = 0; kk < 2; ++kk) {
      const int cb = quad + 4 * kk;
      bf16x8 a_hi = *(const bf16x8*)&eN[rowA * 64 + ((cb) ^ lr) * 4];
      bf16x8 a_lo = *(const bf16x8*)&eN[rowA * 64 + ((cb + 8) ^ lr) * 4];
      int rowB0 = ct0 * 16 + lr, rowB1 = rowB0 + 16;
      bf16x8 b0_hi = *(const bf16x8*)&eM[rowB0 * 64 + ((cb) ^ lr) * 4];
      bf16x8 b0_lo = *(const bf16x8*)&eM[rowB0 * 64 + ((cb + 8) ^ lr) * 4];
      bf16x8 b1_hi = *(const bf16x8*)&eM[rowB1 * 64 + ((cb) ^ lr) * 4];
      bf16x8 b1_lo = *(const bf16x8*)&eM[rowB1 * 64 + ((cb + 8) ^ lr) * 4];
      acc0 = __builtin_amdgcn_mfma_f32_16x16x32_bf16(a_hi, b0_hi, acc0, 0, 0, 0);
      acc0 = __builtin_amdgcn_mfma_f32_16x16x32_bf16(a_hi, b0_lo, acc0, 0, 0, 0);
      acc0 = __builtin_amdgcn_mfma_f32_16x16x32_bf16(a_lo, b0_hi, acc0, 0, 0, 0);
      acc1 = __builtin_amdgcn_mfma_f32_16x16x32_bf16(a_hi, b1_hi, acc1, 0, 0, 0);
      acc1 = __builtin_amdgcn_mfma_f32_16x16x32_bf16(a_hi, b1_lo, acc1, 0, 0, 0);
      acc1 = __builtin_amdgcn_mfma_f32_16x16x32_bf16(a_lo, b1_hi, acc1, 0, 0, 0);
    }
#pragma unroll
    for (int reg = 0; reg < 4; ++reg) {
      int row = rt * 16 + quad * 4 + reg;
      int c0 = ct0 * 16 + lr, c1 = c0 + 16;
      float d20 = fmaxf(sqN[row] + sqMp[m0 + c0] - 2.f * acc0[reg], 0.f);
      float d21 = fmaxf(sqN[row] + sqMp[m0 + c1] - 2.f * acc1[reg], 0.f);
      d2f[row * 65 + c0] = d20;
      d2f[row * 65 + c1] = d21;
    }
    __syncthreads();  // B2: d2f ready (also: frag reads done -> eM restage safe)

    if (seg < 4) {
#pragma unroll 1
      for (int j = 0; j < 16; ++j) {
        float v = d2f[dr * 65 + seg * 16 + j];
        if (v <= 100.f) {  // exact pre-filter (rank metric == filter metric)
          unsigned long long p =
              ((unsigned long long)__float_as_uint(v) << 32) | (unsigned)(m00 + m0 + seg * 16 + j);
          if (p < lst[23]) {
            lst[23] = p;
#pragma unroll
            for (int t = 23; t >= 1; --t) {
              unsigned long long a = lst[t - 1], bb = lst[t];
              bool sw = bb < a;
              lst[t - 1] = sw ? bb : a;
              lst[t] = sw ? a : bb;
            }
          }
        }
      }
    }
    // seg>=4 waves run ahead to stage next eM; B1 orders drain reads vs d2f overwrite
  }
  __syncthreads();  // tiles dead -> reuse as dump

  if (seg < 4) {
#pragma unroll
    for (int i = 0; i < 24; ++i) dump[((seg << 6) | dr) * 24 + i] = lst[i];
  }
  __syncthreads();

  if (tid < 64) {
    int pp[4] = {0, 0, 0, 0};
    unsigned long long h[4];
#pragma unroll
    for (int t = 0; t < 4; ++t) h[t] = dump[((t << 6) | tid) * 24];
    unsigned long long* op = part + ((size_t)bid * 64 + tid) * 24;
#pragma unroll 1
    for (int k = 0; k < 24; ++k) {
      int bs = 0;
      unsigned long long mv = h[0];
#pragma unroll
      for (int t = 1; t < 4; ++t)
        if (h[t] < mv) { mv = h[t]; bs = t; }
      op[k] = mv;  // sentinels ok; k_merge cuts
      int np = ++pp[bs];
      h[bs] = (np < 24) ? dump[((bs << 6) | tid) * 24 + np] : ~0ULL;
    }
  }
}

// ---------------- K3b: merge 8 sorted partials per row -> row_idx/row_cnt/col_cnt
__global__ __launch_bounds__(256) void k_merge(const unsigned long long* __restrict__ part,
                                               int* __restrict__ row_idx,
                                               int* __restrict__ row_cnt,
                                               int* __restrict__ col_cnt) {
  const int row = blockIdx.x * 256 + threadIdx.x;  // b*4096 + n
  const int b = row >> 12;
  const int n = row & 4095;
  const int nt = n >> 6, r = n & 63;
  const size_t gb = (size_t)(((b << 6) | nt) << 3);  // block base (b,nt,mp=0)
  unsigned long long h[8];
  int pp[8];
#pragma unroll
  for (int t = 0; t < 8; ++t) {
    h[t] = part[((gb + t) * 64 + r) * 24];
    pp[t] = 0;
  }
  int cnt = 0;
  const int base = row * KNN;
  for (int k = 0; k < 24; ++k) {
    int bs = 0;
    unsigned long long mv = h[0];
#pragma unroll
    for (int t = 1; t < 8; ++t)
      if (h[t] < mv) { mv = h[t]; bs = t; }
    if ((unsigned)(mv >> 32) > 0x42C80000u) break;  // sentinel / beyond threshold
    int mi = (int)(mv & 0xFFFFFFFFu);
    row_idx[base + cnt] = mi;
    atomicAdd(&col_cnt[(b << 12) + mi], 1);
    ++cnt;
    int np = ++pp[bs];
    h[bs] = (np < 24) ? part[((gb + bs) * 64 + r) * 24 + np] : ~0ULL;
  }
  row_cnt[row] = cnt;
#pragma unroll 4
  for (int j = cnt; j < 24; ++j) row_idx[base + j] = n;  // pad with self (valid gather idx)
}

// ---------------- K4: exclusive scan of col_cnt (16384 entries), 1 block
__global__ __launch_bounds__(256) void k_scan(const int* __restrict__ col_cnt,
                                              int* __restrict__ col_start,
                                              int* __restrict__ col_cursor) {
  __shared__ int part[256];
  const int tid = threadIdx.x;
  const int base = tid * 64;
  int s = 0;
  for (int j = 0; j < 64; ++j) s += col_cnt[base + j];
  part[tid] = s;
  __syncthreads();
  for (int off = 1; off < 256; off <<= 1) {
    int v = (tid >= off) ? part[tid - off] : 0;
    __syncthreads();
    part[tid] += v;
    __syncthreads();
  }
  int run = part[tid] - s;
  for (int j = 0; j < 64; ++j) {
    col_start[base + j] = run;
    col_cursor[base + j] = run;
    run += col_cnt[base + j];
  }
}

// ---------------- K5: fill CSC column lists
__global__ __launch_bounds__(256) void k_fill(const int* __restrict__ row_idx,
                                              const int* __restrict__ row_cnt,
                                              int* __restrict__ col_cursor,
                                              int* __restrict__ col_list) {
  const int row = blockIdx.x * 256 + threadIdx.x;
  const int b = row >> 12;
  const int cnt = row_cnt[row];
  for (int j = 0; j < cnt; ++j) {
    int m = row_idx[row * KNN + j];
    int pos = atomicAdd(&col_cursor[(b << 12) + m], 1);
    col_list[pos] = row & 4095;
  }
}

// ---------------- K6: Yd[e,c] = (sum_{m in col(e)} X_lin[m,c]) / De[e]
__global__ __launch_bounds__(256) void k_yd(const float* __restrict__ xlin,
                                            const int* __restrict__ col_cnt,
                                            const int* __restrict__ col_start,
                                            const int* __restrict__ col_list,
                                            float* __restrict__ yd) {
  const int le = threadIdx.x >> 6;
  const int c4 = threadIdx.x & 63;
  const int be = blockIdx.x * 4 + le;
  const int b = be >> 12;
  const int deg = col_cnt[be];
  const int start = col_start[be];
  float4 acc = make_float4(0.f, 0.f, 0.f, 0.f);
  int j = 0;
  for (; j + 3 < deg; j += 4) {
    int ma = col_list[start + j], mb2 = col_list[start + j + 1];
    int mc = col_list[start + j + 2], md = col_list[start + j + 3];
    float4 va = *(const float4*)&xlin[(((size_t)(b << 12) + ma) << 8) + c4 * 4];
    float4 vb = *(const float4*)&xlin[(((size_t)(b << 12) + mb2) << 8) + c4 * 4];
    float4 vc = *(const float4*)&xlin[(((size_t)(b << 12) + mc) << 8) + c4 * 4];
    float4 vd = *(const float4*)&xlin[(((size_t)(b << 12) + md) << 8) + c4 * 4];
    acc.x += (va.x + vb.x) + (vc.x + vd.x);
    acc.y += (va.y + vb.y) + (vc.y + vd.y);
    acc.z += (va.z + vb.z) + (vc.z + vd.z);
    acc.w += (va.w + vb.w) + (vc.w + vd.w);
  }
  for (; j < deg; ++j) {
    int m = col_list[start + j];
    float4 v = *(const float4*)&xlin[(((size_t)(b << 12) + m) << 8) + c4 * 4];
    acc.x += v.x; acc.y += v.y; acc.z += v.z; acc.w += v.w;
  }
  float inv = 1.f / (float)deg;
  acc.x *= inv; acc.y *= inv; acc.z *= inv; acc.w *= inv;
  *(float4*)&yd[((size_t)be << 8) + c4 * 4] = acc;
}

// ---------------- K7: g[n,c] = (sum_{e in row(n)} Yd[e,c]) / Dv[n]
__global__ __launch_bounds__(256) void k_out2(const float* __restrict__ yd,
                                              const int* __restrict__ row_idx,
                                              const int* __restrict__ row_cnt,
                                              float* __restrict__ outf) {
  const int b = blockIdx.x >> 8;
  const int nt = blockIdx.x & 255;
  const int le = threadIdx.x >> 6;
  const int c4 = threadIdx.x & 63;
  for (int ii = 0; ii < 4; ++ii) {
    int n = nt * 16 + le * 4 + ii;
    int row = (b << 12) + n;
    int cnt = row_cnt[row];
    int idx[24];
    const int4* ip = (const int4*)(row_idx + (size_t)row * KNN);
#pragma unroll
    for (int t = 0; t < 6; ++t) {
      int4 v = ip[t];
      idx[4 * t] = v.x; idx[4 * t + 1] = v.y; idx[4 * t + 2] = v.z; idx[4 * t + 3] = v.w;
    }
    float4 acc = make_float4(0.f, 0.f, 0.f, 0.f);
#pragma unroll
    for (int j = 0; j < 24; ++j) {
      float wgt = (j < cnt) ? 1.f : 0.f;
      float4 v = *(const float4*)&yd[(((size_t)(b << 12) + idx[j]) << 8) + c4 * 4];
      acc.x = fmaf(wgt, v.x, acc.x);
      acc.y = fmaf(wgt, v.y, acc.y);
      acc.z = fmaf(wgt, v.z, acc.z);
      acc.w = fmaf(wgt, v.w, acc.w);
    }
    float inv = 1.f / (float)cnt;
    acc.x *= inv; acc.y *= inv; acc.z *= inv; acc.w *= inv;
    *(float4*)&outf[((size_t)row << 8) + c4 * 4] = acc;
  }
}

// ---------------- K8: outf += x (residual, via LDS transpose); accumulate BN sums
__global__ __launch_bounds__(256) void k_res_bn(const float* __restrict__ x,
                                                float* __restrict__ outf,
                                                float* __restrict__ bn_sum,
                                                float* __restrict__ bn_sumsq) {
  __shared__ float xt[256 * 69];
  const int b = blockIdx.x >> 6;
  const int n0 = (blockIdx.x & 63) << 6;
  const int tid = threadIdx.x;
#pragma unroll 4
  for (int k = 0; k < 16; ++k) {
    int q = tid + 256 * k;
    int c = q >> 4, f = q & 15;
    float4 v = *(const float4*)&x[((size_t)(b * CD + c)) * NB + n0 + 4 * f];
    xt[c * 69 + 4 * f + 0] = v.x;
    xt[c * 69 + 4 * f + 1] = v.y;
    xt[c * 69 + 4 * f + 2] = v.z;
    xt[c * 69 + 4 * f + 3] = v.w;
  }
  __syncthreads();
  float s = 0.f, q = 0.f;
  const size_t rbase = ((size_t)((b << 12) + n0)) << 8;
#pragma unroll 4
  for (int i = 0; i < 64; ++i) {
    float v = outf[rbase + (size_t)i * 256 + tid] + xt[tid * 69 + i];
    outf[rbase + (size_t)i * 256 + tid] = v;
    s += v;
    q = fmaf(v, v, q);
  }
  atomicAdd(&bn_sum[tid], s);
  atomicAdd(&bn_sumsq[tid], q);
}

// ---------------- K9: BN scale/shift per channel
__global__ __launch_bounds__(256) void k_bn(const float* __restrict__ bn_sum,
                                            const float* __restrict__ bn_sumsq,
                                            const float* __restrict__ gamma,
                                            const float* __restrict__ beta,
                                            float* __restrict__ scale,
                                            float* __restrict__ shift) {
  const int c = threadIdx.x;
  const float inv = 1.f / 16384.f;
  float mean = bn_sum[c] * inv;
  float var = bn_sumsq[c] * inv - mean * mean;
  float sc = gamma[c] * rsqrtf(var + 1e-5f);
  scale[c] = sc;
  shift[c] = beta[c] - mean * sc;
}

// ---------------- K10: normalize + SiLU + transpose to [B,C,N]
__global__ __launch_bounds__(256) void k_write(const float* __restrict__ outf,
                                               const float* __restrict__ scale,
                                               const float* __restrict__ shift,
                                               float* __restrict__ out) {
  __shared__ float tile[64 * 257];
  __shared__ float sc[256], sh[256];
  const int b = blockIdx.x >> 6;
  const int n0 = (blockIdx.x & 63) << 6;
  const int tid = threadIdx.x;
  sc[tid] = scale[tid];
  sh[tid] = shift[tid];
  __syncthreads();
#pragma unroll 4
  for (int i = 0; i < 64; ++i) {
    int idx = tid + 256 * i;
    int n = idx >> 8, c = idx & 255;
    float v = outf[(((size_t)(b << 12) + n0 + n) << 8) + c];
    v = fmaf(v, sc[c], sh[c]);
    float w = v / (1.f + expf(-v));  // SiLU
    tile[n * 257 + c] = w;
  }
  __syncthreads();
  const int nl = tid & 63;
  const int cg = tid >> 6;
#pragma unroll 4
  for (int j = 0; j < 64; ++j) {
    int c = cg * 64 + j;
    out[((size_t)(b * CD + c)) * NB + n0 + nl] = tile[nl * 257 + c];
  }
}

extern "C" void kernel_launch(void* const* d_in, const int* in_sizes, int n_in,
                              void* d_out, int out_size, void* d_ws, size_t ws_size,
                              hipStream_t stream) {
  const float* x      = (const float*)d_in[0];
  const float* fc_w   = (const float*)d_in[1];
  const float* fc_b   = (const float*)d_in[2];
  const float* dist_w = (const float*)d_in[3];
  const float* gamma  = (const float*)d_in[4];
  const float* beta   = (const float*)d_in[5];
  float* out = (float*)d_out;
  char* ws = (char*)d_ws;

  const size_t OFF_EHL   = 0;                   // 4 MB
  const size_t OFF_XLIN  = (size_t)4 << 20;     // 16 MB
  const size_t OFF_YD    = (size_t)20 << 20;    // 16 MB (part buffer overlays yd+outf: both dead then)
  const size_t OFF_OUTF  = (size_t)36 << 20;    // 16 MB
  const size_t OFF_SQ    = (size_t)52 << 20;
  const size_t OFF_RIDX  = OFF_SQ + 65536;
  const size_t OFF_RCNT  = OFF_RIDX + 1572864;
  const size_t OFF_CCNT  = OFF_RCNT + 65536;
  const size_t OFF_CSTART = OFF_CCNT + 65536;
  const size_t OFF_CCUR  = OFF_CSTART + 65536;
  const size_t OFF_CLIST = OFF_CCUR + 65536;
  const size_t OFF_BNS   = OFF_CLIST + 1572864;
  const size_t OFF_BNQ   = OFF_BNS + 1024;
  const size_t OFF_SCALE = OFF_BNQ + 1024;
  const size_t OFF_SHIFT = OFF_SCALE + 1024;
  const size_t TOTAL = OFF_SHIFT + 1024;
  if (ws_size < TOTAL) return;

  unsigned* emb_hl = (unsigned*)(ws + OFF_EHL);
  float* xlin  = (float*)(ws + OFF_XLIN);
  float* yd    = (float*)(ws + OFF_YD);
  float* outf  = (float*)(ws + OFF_OUTF);
  unsigned long long* part = (unsigned long long*)(ws + OFF_YD);  // 25.2 MB overlay (yd+outf dead here)
  float* sq    = (float*)(ws + OFF_SQ);
  int* row_idx = (int*)(ws + OFF_RIDX);
  int* row_cnt = (int*)(ws + OFF_RCNT);
  int* col_cnt = (int*)(ws + OFF_CCNT);
  int* col_start = (int*)(ws + OFF_CSTART);
  int* col_cursor = (int*)(ws + OFF_CCUR);
  int* col_list = (int*)(ws + OFF_CLIST);
  float* bn_sum = (float*)(ws + OFF_BNS);
  float* bn_sumsq = (float*)(ws + OFF_BNQ);
  float* scale = (float*)(ws + OFF_SCALE);
  float* shift = (float*)(ws + OFF_SHIFT);

  hipMemsetAsync(col_cnt, 0, 65536, stream);
  hipMemsetAsync(bn_sum, 0, 2048, stream);

  k_emb<<<256, 256, 0, stream>>>(x, dist_w, emb_hl, sq);
  k_xlin<<<256, 256, 0, stream>>>(x, fc_w, fc_b, xlin);
  k_distp<<<2048, 512, 0, stream>>>(emb_hl, sq, part);
  k_merge<<<64, 256, 0, stream>>>(part, row_idx, row_cnt, col_cnt);
  k_scan<<<1, 256, 0, stream>>>(col_cnt, col_start, col_cursor);
  k_fill<<<64, 256, 0, stream>>>(row_idx, row_cnt, col_cursor, col_list);
  k_yd<<<4096, 256, 0, stream>>>(xlin, col_cnt, col_start, col_list, yd);
  k_out2<<<1024, 256, 0, stream>>>(yd, row_idx, row_cnt, outf);
  k_res_bn<<<256, 256, 0, stream>>>(x, outf, bn_sum, bn_sumsq);
  k_bn<<<1, 256, 0, stream>>>(bn_sum, bn_sumsq, gamma, beta, scale, shift);
  k_write<<<256, 256, 0, stream>>>(outf, scale, shift, out);
}

// Round 8
// 701.363 us; speedup vs baseline: 1.7837x; 1.0492x over previous
//
#include <hip/hip_runtime.h>

#define NB 4096      // N = H*W
#define BATCH 4
#define CD 256       // channels
#define ED 64        // embedding dim
#define KNN 24

typedef __attribute__((ext_vector_type(8))) short bf16x8;
typedef __attribute__((ext_vector_type(4))) float f32x4;

__device__ __forceinline__ unsigned short f2bf(float x) {
  unsigned u = __float_as_uint(x);
  unsigned r = (u + 0x7fffu + ((u >> 16) & 1u)) >> 16;
  return (unsigned short)r;
}

// ---------------- K1: emb = x @ dist_w^T  -> emb_hl (bf16 hi/lo, XOR-swizzled chunks) + sq (fp32)
__global__ __launch_bounds__(256) void k_emb(const float* __restrict__ x,
                                             const float* __restrict__ dist_w,
                                             unsigned* __restrict__ emb_hl,
                                             float* __restrict__ sq) {
  __shared__ float wds[ED * CD];   // 64 KB
  __shared__ float red[64 * 4];
  const int b = blockIdx.x >> 6;
  const int n0 = (blockIdx.x & 63) << 6;
  const int tid = threadIdx.x;
  const float4* wsrc = (const float4*)dist_w;
  float4* wdst = (float4*)wds;
#pragma unroll
  for (int k = 0; k < 16; ++k) wdst[tid + 256 * k] = wsrc[tid + 256 * k];
  __syncthreads();
  const int eg = tid >> 6;   // 0..3
  const int nl = tid & 63;
  const int n = n0 + nl;
  float acc[16];
#pragma unroll
  for (int t = 0; t < 16; ++t) acc[t] = 0.f;
  const float* xb = x + (size_t)b * CD * NB + n;
#pragma unroll 4
  for (int c = 0; c < CD; ++c) {
    float xv = xb[(size_t)c * NB];
#pragma unroll
    for (int t = 0; t < 16; ++t)
      acc[t] = fmaf(xv, wds[(eg * 16 + t) * CD + c], acc[t]);
  }
  float s = 0.f;
#pragma unroll
  for (int t = 0; t < 16; ++t) s = fmaf(acc[t], acc[t], s);
  unsigned hw[8], lw[8];
#pragma unroll
  for (int i = 0; i < 8; ++i) {
    unsigned short h0 = f2bf(acc[2 * i]);
    unsigned short h1 = f2bf(acc[2 * i + 1]);
    float l0f = acc[2 * i] - __uint_as_float((unsigned)h0 << 16);
    float l1f = acc[2 * i + 1] - __uint_as_float((unsigned)h1 << 16);
    hw[i] = (unsigned)h0 | ((unsigned)h1 << 16);
    lw[i] = (unsigned)f2bf(l0f) | ((unsigned)f2bf(l1f) << 16);
  }
  uint4* g = (uint4*)emb_hl;
  const size_t gb = ((size_t)(b * NB + n)) * 16;
  const int k15 = n & 15;
  g[gb + ((2 * eg) ^ k15)]     = make_uint4(hw[0], hw[1], hw[2], hw[3]);
  g[gb + ((2 * eg + 1) ^ k15)] = make_uint4(hw[4], hw[5], hw[6], hw[7]);
  g[gb + ((8 + 2 * eg) ^ k15)]     = make_uint4(lw[0], lw[1], lw[2], lw[3]);
  g[gb + ((8 + 2 * eg + 1) ^ k15)] = make_uint4(lw[4], lw[5], lw[6], lw[7]);
  red[nl * 4 + eg] = s;
  __syncthreads();
  if (tid < 64)
    sq[b * NB + n0 + tid] = red[tid * 4] + red[tid * 4 + 1] + red[tid * 4 + 2] + red[tid * 4 + 3];
}

// ---------------- K2: X_lin[b,n,c] = sum_k x[b,k,n]*fc_w[c,k] + fc_b[c]
__global__ __launch_bounds__(256) void k_xlin(const float* __restrict__ x,
                                              const float* __restrict__ fc_w,
                                              const float* __restrict__ fc_b,
                                              float* __restrict__ xlin) {
  __shared__ float xt[64 * 64];     // [k][n]
  __shared__ float wt[64 * 260];    // [k][c] padded
  const int b = blockIdx.x >> 6;
  const int n0 = (blockIdx.x & 63) << 6;
  const int tid = threadIdx.x;
  const int nl4 = tid & 15;
  const int cg = tid >> 4;
  float acc[4][16];
#pragma unroll
  for (int i = 0; i < 4; ++i)
#pragma unroll
    for (int j = 0; j < 16; ++j) acc[i][j] = 0.f;

  for (int kt = 0; kt < 4; ++kt) {
    __syncthreads();
#pragma unroll 4
    for (int i = 0; i < 16; ++i) {
      int idx = tid + 256 * i;
      int k = idx >> 6, n = idx & 63;
      xt[idx] = x[((size_t)(b * CD + kt * 64 + k)) * NB + n0 + n];
    }
#pragma unroll 4
    for (int i = 0; i < 16; ++i) {
      int q = tid + 256 * i;
      int c = q >> 4, k4 = (q & 15) * 4;
      float4 v = *(const float4*)&fc_w[(size_t)c * CD + kt * 64 + k4];
      wt[(k4 + 0) * 260 + c] = v.x;
      wt[(k4 + 1) * 260 + c] = v.y;
      wt[(k4 + 2) * 260 + c] = v.z;
      wt[(k4 + 3) * 260 + c] = v.w;
    }
    __syncthreads();
#pragma unroll 2
    for (int k = 0; k < 64; ++k) {
      float4 xv = *(const float4*)&xt[k * 64 + 4 * nl4];
#pragma unroll
      for (int j = 0; j < 4; ++j) {
        float4 wv = *(const float4*)&wt[k * 260 + 4 * cg + 64 * j];
        const float* wp = &wv.x;
#pragma unroll
        for (int l = 0; l < 4; ++l) {
          acc[0][4 * j + l] = fmaf(xv.x, wp[l], acc[0][4 * j + l]);
          acc[1][4 * j + l] = fmaf(xv.y, wp[l], acc[1][4 * j + l]);
          acc[2][4 * j + l] = fmaf(xv.z, wp[l], acc[2][4 * j + l]);
          acc[3][4 * j + l] = fmaf(xv.w, wp[l], acc[3][4 * j + l]);
        }
      }
    }
  }
#pragma unroll
  for (int i = 0; i < 4; ++i) {
    int n = n0 + 4 * nl4 + i;
    float* dst = xlin + ((size_t)(b * NB + n)) * CD;
#pragma unroll
    for (int j = 0; j < 4; ++j) {
      int c = 4 * cg + 64 * j;
      float4 bv = *(const float4*)&fc_b[c];
      float4 o;
      o.x = acc[i][4 * j + 0] + bv.x;
      o.y = acc[i][4 * j + 1] + bv.y;
      o.z = acc[i][4 * j + 2] + bv.z;
      o.w = acc[i][4 * j + 3] + bv.w;
      *(float4*)&dst[c] = o;
    }
  }
}

// insert p into sorted 24-list (ascending, strict compares -> stable, exact)
#define INSERT24(p)                                        \
  if ((p) < lst[23]) {                                     \
    lst[23] = (p);                                         \
    _Pragma("unroll")                                      \
    for (int t = 23; t >= 1; --t) {                        \
      unsigned long long a_ = lst[t - 1], b_ = lst[t];     \
      bool sw_ = b_ < a_;                                  \
      lst[t - 1] = sw_ ? b_ : a_;                          \
      lst[t] = sw_ ? a_ : b_;                              \
    }                                                      \
  }

// ---------------- K3 v8: m-split partial kNN; per-lane 4-slot candidate queue batches the
// expensive sorted-insert (wave-union cost: ~every step paid 23-stage swap; now only on
// __any(queue full) -> ~4-16x fewer flushes). Comparator & order bit-identical to v7.
__global__ __launch_bounds__(512, 4) void k_distp(const unsigned* __restrict__ emb_hl,
                                                  const float* __restrict__ sq,
                                                  unsigned long long* __restrict__ part) {
  __shared__ __align__(16) unsigned char smem[51712];
  unsigned* eN = (unsigned*)smem;                        // 16384 B
  unsigned* eM = (unsigned*)(smem + 16384);              // 16384 B
  float* d2f   = (float*)(smem + 32768);                 // 16640 B (64 x 65)
  float* sqN   = (float*)(smem + 49408);                 // 256 B
  float* sqMp  = (float*)(smem + 49664);                 // 2048 B (512 m of this part)
  unsigned long long* dump = (unsigned long long*)smem;  // overlay phase 2: 49152 B (4x64x24)

  const int bid = blockIdx.x;
  const int mp = bid & 7;
  const int nt = (bid >> 3) & 63;
  const int b  = bid >> 9;
  const int n0 = nt << 6;
  const int m00 = mp << 9;   // global m base of this part
  const int tid = threadIdx.x;
  const uint4* embg = (const uint4*)emb_hl;
  const size_t bbase = (size_t)b * NB;

#pragma unroll
  for (int k = 0; k < 2; ++k) {
    int q = tid + 512 * k;
    int r = q >> 4, ch = q & 15;
    *(uint4*)&eN[r * 64 + ch * 4] = embg[(bbase + n0 + r) * 16 + ch];
  }
  if (tid < 64) sqN[tid] = sq[b * NB + n0 + tid];
  sqMp[tid] = sq[b * NB + m00 + tid];

  const int w = tid >> 6, lane = tid & 63;
  const int quad = lane >> 4, lr = lane & 15;
  const int rt = w >> 1;            // row tile 0..3
  const int ct0 = (w & 1) * 2;      // first of my 2 col tiles (of 4)
  const int rowA = rt * 16 + lr;

  const int seg = tid >> 6;         // 0..7; only seg<4 drain (16 cols each)
  const int dr = tid & 63;

  unsigned long long lst[24];
#pragma unroll
  for (int i = 0; i < 24; ++i) lst[i] = ~0ULL;
  unsigned long long q0 = 0, q1 = 0, q2 = 0, q3 = 0;  // pending-candidate queue
  int qc = 0;

  for (int ci = 0; ci < 8; ++ci) {
    const int m0 = ci << 6;  // local m offset
#pragma unroll
    for (int k = 0; k < 2; ++k) {
      int q = tid + 512 * k;
      int r = q >> 4, ch = q & 15;
      *(uint4*)&eM[r * 64 + ch * 4] = embg[(bbase + m00 + m0 + r) * 16 + ch];
    }
    __syncthreads();  // B1: eM ready AND previous drain done

    f32x4 acc0 = {0.f, 0.f, 0.f, 0.f};
    f32x4 acc1 = {0.f, 0.f, 0.f, 0.f};
#pragma unroll
    for (int kk = 0; kk < 2; ++kk) {
      const int cb = quad + 4 * kk;
      bf16x8 a_hi = *(const bf16x8*)&eN[rowA * 64 + ((cb) ^ lr) * 4];
      bf16x8 a_lo = *(const bf16x8*)&eN[rowA * 64 + ((cb + 8) ^ lr) * 4];
      int rowB0 = ct0 * 16 + lr, rowB1 = rowB0 + 16;
      bf16x8 b0_hi = *(const bf16x8*)&eM[rowB0 * 64 + ((cb) ^ lr) * 4];
      bf16x8 b0_lo = *(const bf16x8*)&eM[rowB0 * 64 + ((cb + 8) ^ lr) * 4];
      bf16x8 b1_hi = *(const bf16x8*)&eM[rowB1 * 64 + ((cb) ^ lr) * 4];
      bf16x8 b1_lo = *(const bf16x8*)&eM[rowB1 * 64 + ((cb + 8) ^ lr) * 4];
      acc0 = __builtin_amdgcn_mfma_f32_16x16x32_bf16(a_hi, b0_hi, acc0, 0, 0, 0);
      acc0 = __builtin_amdgcn_mfma_f32_16x16x32_bf16(a_hi, b0_lo, acc0, 0, 0, 0);
      acc0 = __builtin_amdgcn_mfma_f32_16x16x32_bf16(a_lo, b0_hi, acc0, 0, 0, 0);
      acc1 = __builtin_amdgcn_mfma_f32_16x16x32_bf16(a_hi, b1_hi, acc1, 0, 0, 0);
      acc1 = __builtin_amdgcn_mfma_f32_16x16x32_bf16(a_hi, b1_lo, acc1, 0, 0, 0);
      acc1 = __builtin_amdgcn_mfma_f32_16x16x32_bf16(a_lo, b1_hi, acc1, 0, 0, 0);
    }
#pragma unroll
    for (int reg = 0; reg < 4; ++reg) {
      int row = rt * 16 + quad * 4 + reg;
      int c0 = ct0 * 16 + lr, c1 = c0 + 16;
      float d20 = fmaxf(sqN[row] + sqMp[m0 + c0] - 2.f * acc0[reg], 0.f);
      float d21 = fmaxf(sqN[row] + sqMp[m0 + c1] - 2.f * acc1[reg], 0.f);
      d2f[row * 65 + c0] = d20;
      d2f[row * 65 + c1] = d21;
    }
    __syncthreads();  // B2: d2f ready (also: frag reads done -> eM restage safe)

    if (seg < 4) {  // wave-uniform branch (seg == wave id)
#pragma unroll 1
      for (int j = 0; j < 16; ++j) {
        float v = d2f[dr * 65 + seg * 16 + j];
        if (v <= 100.f) {  // exact pre-filter (rank metric == filter metric)
          unsigned long long p =
              ((unsigned long long)__float_as_uint(v) << 32) | (unsigned)(m00 + m0 + seg * 16 + j);
          q0 = (qc == 0) ? p : q0;
          q1 = (qc == 1) ? p : q1;
          q2 = (qc == 2) ? p : q2;
          q3 = (qc == 3) ? p : q3;
          ++qc;
        }
        if (__any(qc >= 4)) {  // batched flush: arrival order preserved -> semantics identical
          if (qc > 0) { INSERT24(q0) }
          if (qc > 1) { INSERT24(q1) }
          if (qc > 2) { INSERT24(q2) }
          if (qc > 3) { INSERT24(q3) }
          qc = 0;
        }
      }
    }
    // seg>=4 waves run ahead to stage next eM; B1 orders drain reads vs d2f overwrite
  }
  // final flush of pending candidates
  if (seg < 4) {
    if (qc > 0) { INSERT24(q0) }
    if (qc > 1) { INSERT24(q1) }
    if (qc > 2) { INSERT24(q2) }
    if (qc > 3) { INSERT24(q3) }
  }
  __syncthreads();  // tiles dead -> reuse as dump

  if (seg < 4) {
#pragma unroll
    for (int i = 0; i < 24; ++i) dump[((seg << 6) | dr) * 24 + i] = lst[i];
  }
  __syncthreads();

  if (tid < 64) {
    int pp[4] = {0, 0, 0, 0};
    unsigned long long h[4];
#pragma unroll
    for (int t = 0; t < 4; ++t) h[t] = dump[((t << 6) | tid) * 24];
    unsigned long long* op = part + ((size_t)bid * 64 + tid) * 24;
#pragma unroll 1
    for (int k = 0; k < 24; ++k) {
      int bs = 0;
      unsigned long long mv = h[0];
#pragma unroll
      for (int t = 1; t < 4; ++t)
        if (h[t] < mv) { mv = h[t]; bs = t; }
      op[k] = mv;  // sentinels ok; k_merge cuts
      int np = ++pp[bs];
      h[bs] = (np < 24) ? dump[((bs << 6) | tid) * 24 + np] : ~0ULL;
    }
  }
}

// ---------------- K3b: merge 8 sorted partials per row -> row_idx/row_cnt/col_cnt
__global__ __launch_bounds__(256) void k_merge(const unsigned long long* __restrict__ part,
                                               int* __restrict__ row_idx,
                                               int* __restrict__ row_cnt,
                                               int* __restrict__ col_cnt) {
  const int row = blockIdx.x * 256 + threadIdx.x;  // b*4096 + n
  const int b = row >> 12;
  const int n = row & 4095;
  const int nt = n >> 6, r = n & 63;
  const size_t gb = (size_t)(((b << 6) | nt) << 3);  // block base (b,nt,mp=0)
  unsigned long long h[8];
  int pp[8];
#pragma unroll
  for (int t = 0; t < 8; ++t) {
    h[t] = part[((gb + t) * 64 + r) * 24];
    pp[t] = 0;
  }
  int cnt = 0;
  const int base = row * KNN;
  for (int k = 0; k < 24; ++k) {
    int bs = 0;
    unsigned long long mv = h[0];
#pragma unroll
    for (int t = 1; t < 8; ++t)
      if (h[t] < mv) { mv = h[t]; bs = t; }
    if ((unsigned)(mv >> 32) > 0x42C80000u) break;  // sentinel / beyond threshold
    int mi = (int)(mv & 0xFFFFFFFFu);
    row_idx[base + cnt] = mi;
    atomicAdd(&col_cnt[(b << 12) + mi], 1);
    ++cnt;
    int np = ++pp[bs];
    h[bs] = (np < 24) ? part[((gb + bs) * 64 + r) * 24 + np] : ~0ULL;
  }
  row_cnt[row] = cnt;
#pragma unroll 4
  for (int j = cnt; j < 24; ++j) row_idx[base + j] = n;  // pad with self (valid gather idx)
}

// ---------------- K4: exclusive scan of col_cnt (16384 entries), 1 block
__global__ __launch_bounds__(256) void k_scan(const int* __restrict__ col_cnt,
                                              int* __restrict__ col_start,
                                              int* __restrict__ col_cursor) {
  __shared__ int part[256];
  const int tid = threadIdx.x;
  const int base = tid * 64;
  int s = 0;
  for (int j = 0; j < 64; ++j) s += col_cnt[base + j];
  part[tid] = s;
  __syncthreads();
  for (int off = 1; off < 256; off <<= 1) {
    int v = (tid >= off) ? part[tid - off] : 0;
    __syncthreads();
    part[tid] += v;
    __syncthreads();
  }
  int run = part[tid] - s;
  for (int j = 0; j < 64; ++j) {
    col_start[base + j] = run;
    col_cursor[base + j] = run;
    run += col_cnt[base + j];
  }
}

// ---------------- K5: fill CSC column lists
__global__ __launch_bounds__(256) void k_fill(const int* __restrict__ row_idx,
                                              const int* __restrict__ row_cnt,
                                              int* __restrict__ col_cursor,
                                              int* __restrict__ col_list) {
  const int row = blockIdx.x * 256 + threadIdx.x;
  const int b = row >> 12;
  const int cnt = row_cnt[row];
  for (int j = 0; j < cnt; ++j) {
    int m = row_idx[row * KNN + j];
    int pos = atomicAdd(&col_cursor[(b << 12) + m], 1);
    col_list[pos] = row & 4095;
  }
}

// ---------------- K6: Yd[e,c] = (sum_{m in col(e)} X_lin[m,c]) / De[e]
__global__ __launch_bounds__(256) void k_yd(const float* __restrict__ xlin,
                                            const int* __restrict__ col_cnt,
                                            const int* __restrict__ col_start,
                                            const int* __restrict__ col_list,
                                            float* __restrict__ yd) {
  const int le = threadIdx.x >> 6;
  const int c4 = threadIdx.x & 63;
  const int be = blockIdx.x * 4 + le;
  const int b = be >> 12;
  const int deg = col_cnt[be];
  const int start = col_start[be];
  float4 acc = make_float4(0.f, 0.f, 0.f, 0.f);
  int j = 0;
  for (; j + 3 < deg; j += 4) {
    int ma = col_list[start + j], mb2 = col_list[start + j + 1];
    int mc = col_list[start + j + 2], md = col_list[start + j + 3];
    float4 va = *(const float4*)&xlin[(((size_t)(b << 12) + ma) << 8) + c4 * 4];
    float4 vb = *(const float4*)&xlin[(((size_t)(b << 12) + mb2) << 8) + c4 * 4];
    float4 vc = *(const float4*)&xlin[(((size_t)(b << 12) + mc) << 8) + c4 * 4];
    float4 vd = *(const float4*)&xlin[(((size_t)(b << 12) + md) << 8) + c4 * 4];
    acc.x += (va.x + vb.x) + (vc.x + vd.x);
    acc.y += (va.y + vb.y) + (vc.y + vd.y);
    acc.z += (va.z + vb.z) + (vc.z + vd.z);
    acc.w += (va.w + vb.w) + (vc.w + vd.w);
  }
  for (; j < deg; ++j) {
    int m = col_list[start + j];
    float4 v = *(const float4*)&xlin[(((size_t)(b << 12) + m) << 8) + c4 * 4];
    acc.x += v.x; acc.y += v.y; acc.z += v.z; acc.w += v.w;
  }
  float inv = 1.f / (float)deg;
  acc.x *= inv; acc.y *= inv; acc.z *= inv; acc.w *= inv;
  *(float4*)&yd[((size_t)be << 8) + c4 * 4] = acc;
}

// ---------------- K7: g[n,c] = (sum_{e in row(n)} Yd[e,c]) / Dv[n]
__global__ __launch_bounds__(256) void k_out2(const float* __restrict__ yd,
                                              const int* __restrict__ row_idx,
                                              const int* __restrict__ row_cnt,
                                              float* __restrict__ outf) {
  const int b = blockIdx.x >> 8;
  const int nt = blockIdx.x & 255;
  const int le = threadIdx.x >> 6;
  const int c4 = threadIdx.x & 63;
  for (int ii = 0; ii < 4; ++ii) {
    int n = nt * 16 + le * 4 + ii;
    int row = (b << 12) + n;
    int cnt = row_cnt[row];
    int idx[24];
    const int4* ip = (const int4*)(row_idx + (size_t)row * KNN);
#pragma unroll
    for (int t = 0; t < 6; ++t) {
      int4 v = ip[t];
      idx[4 * t] = v.x; idx[4 * t + 1] = v.y; idx[4 * t + 2] = v.z; idx[4 * t + 3] = v.w;
    }
    float4 acc = make_float4(0.f, 0.f, 0.f, 0.f);
#pragma unroll
    for (int j = 0; j < 24; ++j) {
      float wgt = (j < cnt) ? 1.f : 0.f;
      float4 v = *(const float4*)&yd[(((size_t)(b << 12) + idx[j]) << 8) + c4 * 4];
      acc.x = fmaf(wgt, v.x, acc.x);
      acc.y = fmaf(wgt, v.y, acc.y);
      acc.z = fmaf(wgt, v.z, acc.z);
      acc.w = fmaf(wgt, v.w, acc.w);
    }
    float inv = 1.f / (float)cnt;
    acc.x *= inv; acc.y *= inv; acc.z *= inv; acc.w *= inv;
    *(float4*)&outf[((size_t)row << 8) + c4 * 4] = acc;
  }
}

// ---------------- K8: outf += x (residual, via LDS transpose); accumulate BN sums
__global__ __launch_bounds__(256) void k_res_bn(const float* __restrict__ x,
                                                float* __restrict__ outf,
                                                float* __restrict__ bn_sum,
                                                float* __restrict__ bn_sumsq) {
  __shared__ float xt[256 * 69];
  const int b = blockIdx.x >> 6;
  const int n0 = (blockIdx.x & 63) << 6;
  const int tid = threadIdx.x;
#pragma unroll 4
  for (int k = 0; k < 16; ++k) {
    int q = tid + 256 * k;
    int c = q >> 4, f = q & 15;
    float4 v = *(const float4*)&x[((size_t)(b * CD + c)) * NB + n0 + 4 * f];
    xt[c * 69 + 4 * f + 0] = v.x;
    xt[c * 69 + 4 * f + 1] = v.y;
    xt[c * 69 + 4 * f + 2] = v.z;
    xt[c * 69 + 4 * f + 3] = v.w;
  }
  __syncthreads();
  float s = 0.f, q = 0.f;
  const size_t rbase = ((size_t)((b << 12) + n0)) << 8;
#pragma unroll 4
  for (int i = 0; i < 64; ++i) {
    float v = outf[rbase + (size_t)i * 256 + tid] + xt[tid * 69 + i];
    outf[rbase + (size_t)i * 256 + tid] = v;
    s += v;
    q = fmaf(v, v, q);
  }
  atomicAdd(&bn_sum[tid], s);
  atomicAdd(&bn_sumsq[tid], q);
}

// ---------------- K9: BN scale/shift per channel
__global__ __launch_bounds__(256) void k_bn(const float* __restrict__ bn_sum,
                                            const float* __restrict__ bn_sumsq,
                                            const float* __restrict__ gamma,
                                            const float* __restrict__ beta,
                                            float* __restrict__ scale,
                                            float* __restrict__ shift) {
  const int c = threadIdx.x;
  const float inv = 1.f / 16384.f;
  float mean = bn_sum[c] * inv;
  float var = bn_sumsq[c] * inv - mean * mean;
  float sc = gamma[c] * rsqrtf(var + 1e-5f);
  scale[c] = sc;
  shift[c] = beta[c] - mean * sc;
}

// ---------------- K10: normalize + SiLU + transpose to [B,C,N]
__global__ __launch_bounds__(256) void k_write(const float* __restrict__ outf,
                                               const float* __restrict__ scale,
                                               const float* __restrict__ shift,
                                               float* __restrict__ out) {
  __shared__ float tile[64 * 257];
  __shared__ float sc[256], sh[256];
  const int b = blockIdx.x >> 6;
  const int n0 = (blockIdx.x & 63) << 6;
  const int tid = threadIdx.x;
  sc[tid] = scale[tid];
  sh[tid] = shift[tid];
  __syncthreads();
#pragma unroll 4
  for (int i = 0; i < 64; ++i) {
    int idx = tid + 256 * i;
    int n = idx >> 8, c = idx & 255;
    float v = outf[(((size_t)(b << 12) + n0 + n) << 8) + c];
    v = fmaf(v, sc[c], sh[c]);
    float w = v / (1.f + expf(-v));  // SiLU
    tile[n * 257 + c] = w;
  }
  __syncthreads();
  const int nl = tid & 63;
  const int cg = tid >> 6;
#pragma unroll 4
  for (int j = 0; j < 64; ++j) {
    int c = cg * 64 + j;
    out[((size_t)(b * CD + c)) * NB + n0 + nl] = tile[nl * 257 + c];
  }
}

extern "C" void kernel_launch(void* const* d_in, const int* in_sizes, int n_in,
                              void* d_out, int out_size, void* d_ws, size_t ws_size,
                              hipStream_t stream) {
  const float* x      = (const float*)d_in[0];
  const float* fc_w   = (const float*)d_in[1];
  const float* fc_b   = (const float*)d_in[2];
  const float* dist_w = (const float*)d_in[3];
  const float* gamma  = (const float*)d_in[4];
  const float* beta   = (const float*)d_in[5];
  float* out = (float*)d_out;
  char* ws = (char*)d_ws;

  const size_t OFF_EHL   = 0;                   // 4 MB
  const size_t OFF_XLIN  = (size_t)4 << 20;     // 16 MB
  const size_t OFF_YD    = (size_t)20 << 20;    // 16 MB (part buffer overlays yd+outf: both dead then)
  const size_t OFF_OUTF  = (size_t)36 << 20;    // 16 MB
  const size_t OFF_SQ    = (size_t)52 << 20;
  const size_t OFF_RIDX  = OFF_SQ + 65536;
  const size_t OFF_RCNT  = OFF_RIDX + 1572864;
  const size_t OFF_CCNT  = OFF_RCNT + 65536;
  const size_t OFF_CSTART = OFF_CCNT + 65536;
  const size_t OFF_CCUR  = OFF_CSTART + 65536;
  const size_t OFF_CLIST = OFF_CCUR + 65536;
  const size_t OFF_BNS   = OFF_CLIST + 1572864;
  const size_t OFF_BNQ   = OFF_BNS + 1024;
  const size_t OFF_SCALE = OFF_BNQ + 1024;
  const size_t OFF_SHIFT = OFF_SCALE + 1024;
  const size_t TOTAL = OFF_SHIFT + 1024;
  if (ws_size < TOTAL) return;

  unsigned* emb_hl = (unsigned*)(ws + OFF_EHL);
  float* xlin  = (float*)(ws + OFF_XLIN);
  float* yd    = (float*)(ws + OFF_YD);
  float* outf  = (float*)(ws + OFF_OUTF);
  unsigned long long* part = (unsigned long long*)(ws + OFF_YD);  // 25.2 MB overlay (yd+outf dead here)
  float* sq    = (float*)(ws + OFF_SQ);
  int* row_idx = (int*)(ws + OFF_RIDX);
  int* row_cnt = (int*)(ws + OFF_RCNT);
  int* col_cnt = (int*)(ws + OFF_CCNT);
  int* col_start = (int*)(ws + OFF_CSTART);
  int* col_cursor = (int*)(ws + OFF_CCUR);
  int* col_list = (int*)(ws + OFF_CLIST);
  float* bn_sum = (float*)(ws + OFF_BNS);
  float* bn_sumsq = (float*)(ws + OFF_BNQ);
  float* scale = (float*)(ws + OFF_SCALE);
  float* shift = (float*)(ws + OFF_SHIFT);

  hipMemsetAsync(col_cnt, 0, 65536, stream);
  hipMemsetAsync(bn_sum, 0, 2048, stream);

  k_emb<<<256, 256, 0, stream>>>(x, dist_w, emb_hl, sq);
  k_xlin<<<256, 256, 0, stream>>>(x, fc_w, fc_b, xlin);
  k_distp<<<2048, 512, 0, stream>>>(emb_hl, sq, part);
  k_merge<<<64, 256, 0, stream>>>(part, row_idx, row_cnt, col_cnt);
  k_scan<<<1, 256, 0, stream>>>(col_cnt, col_start, col_cursor);
  k_fill<<<64, 256, 0, stream>>>(row_idx, row_cnt, col_cursor, col_list);
  k_yd<<<4096, 256, 0, stream>>>(xlin, col_cnt, col_start, col_list, yd);
  k_out2<<<1024, 256, 0, stream>>>(yd, row_idx, row_cnt, outf);
  k_res_bn<<<256, 256, 0, stream>>>(x, outf, bn_sum, bn_sumsq);
  k_bn<<<1, 256, 0, stream>>>(bn_sum, bn_sumsq, gamma, beta, scale, shift);
  k_write<<<256, 256, 0, stream>>>(outf, scale, shift, out);
}

// Round 10
// 695.932 us; speedup vs baseline: 1.7976x; 1.0078x over previous
//
#include <hip/hip_runtime.h>

#define NB 4096      // N = H*W
#define BATCH 4
#define CD 256       // channels
#define ED 64        // embedding dim
#define KNN 24

typedef __attribute__((ext_vector_type(8))) short bf16x8;
typedef __attribute__((ext_vector_type(4))) float f32x4;

__device__ __forceinline__ unsigned short f2bf(float x) {
  unsigned u = __float_as_uint(x);
  unsigned r = (u + 0x7fffu + ((u >> 16) & 1u)) >> 16;
  return (unsigned short)r;
}

// ---------------- K1: emb = x @ dist_w^T  -> emb_hl (bf16 hi/lo, XOR-swizzled chunks) + sq (fp32)
// v2: float4 weight reads (ds_read_b128, 1 read : 4 FMA vs r8's 1:1 scalar) — same summation
// order (c ascending per accumulator) -> bit-identical output.
__global__ __launch_bounds__(256) void k_emb(const float* __restrict__ x,
                                             const float* __restrict__ dist_w,
                                             unsigned* __restrict__ emb_hl,
                                             float* __restrict__ sq) {
  __shared__ float wds[ED * CD];   // 64 KB
  __shared__ float red[64 * 4];
  const int b = blockIdx.x >> 6;
  const int n0 = (blockIdx.x & 63) << 6;
  const int tid = threadIdx.x;
  const float4* wsrc = (const float4*)dist_w;
  float4* wdst = (float4*)wds;
#pragma unroll
  for (int k = 0; k < 16; ++k) wdst[tid + 256 * k] = wsrc[tid + 256 * k];
  __syncthreads();
  const int eg = tid >> 6;   // 0..3
  const int nl = tid & 63;
  const int n = n0 + nl;
  float acc[16];
#pragma unroll
  for (int t = 0; t < 16; ++t) acc[t] = 0.f;
  const float* xb = x + (size_t)b * CD * NB + n;
#pragma unroll 2
  for (int c4 = 0; c4 < CD; c4 += 4) {
    float x0 = xb[(size_t)(c4 + 0) * NB];
    float x1 = xb[(size_t)(c4 + 1) * NB];
    float x2 = xb[(size_t)(c4 + 2) * NB];
    float x3 = xb[(size_t)(c4 + 3) * NB];
#pragma unroll
    for (int t = 0; t < 16; ++t) {
      float4 wv = *(const float4*)&wds[(eg * 16 + t) * CD + c4];
      acc[t] = fmaf(x0, wv.x, acc[t]);
      acc[t] = fmaf(x1, wv.y, acc[t]);
      acc[t] = fmaf(x2, wv.z, acc[t]);
      acc[t] = fmaf(x3, wv.w, acc[t]);
    }
  }
  float s = 0.f;
#pragma unroll
  for (int t = 0; t < 16; ++t) s = fmaf(acc[t], acc[t], s);
  unsigned hw[8], lw[8];
#pragma unroll
  for (int i = 0; i < 8; ++i) {
    unsigned short h0 = f2bf(acc[2 * i]);
    unsigned short h1 = f2bf(acc[2 * i + 1]);
    float l0f = acc[2 * i] - __uint_as_float((unsigned)h0 << 16);
    float l1f = acc[2 * i + 1] - __uint_as_float((unsigned)h1 << 16);
    hw[i] = (unsigned)h0 | ((unsigned)h1 << 16);
    lw[i] = (unsigned)f2bf(l0f) | ((unsigned)f2bf(l1f) << 16);
  }
  uint4* g = (uint4*)emb_hl;
  const size_t gb = ((size_t)(b * NB + n)) * 16;
  const int k15 = n & 15;
  g[gb + ((2 * eg) ^ k15)]     = make_uint4(hw[0], hw[1], hw[2], hw[3]);
  g[gb + ((2 * eg + 1) ^ k15)] = make_uint4(hw[4], hw[5], hw[6], hw[7]);
  g[gb + ((8 + 2 * eg) ^ k15)]     = make_uint4(lw[0], lw[1], lw[2], lw[3]);
  g[gb + ((8 + 2 * eg + 1) ^ k15)] = make_uint4(lw[4], lw[5], lw[6], lw[7]);
  red[nl * 4 + eg] = s;
  __syncthreads();
  if (tid < 64)
    sq[b * NB + n0 + tid] = red[tid * 4] + red[tid * 4 + 1] + red[tid * 4 + 2] + red[tid * 4 + 3];
}

// ---------------- K2: X_lin[b,n,c] = sum_k x[b,k,n]*fc_w[c,k] + fc_b[c]
__global__ __launch_bounds__(256) void k_xlin(const float* __restrict__ x,
                                              const float* __restrict__ fc_w,
                                              const float* __restrict__ fc_b,
                                              float* __restrict__ xlin) {
  __shared__ float xt[64 * 64];     // [k][n]
  __shared__ float wt[64 * 260];    // [k][c] padded
  const int b = blockIdx.x >> 6;
  const int n0 = (blockIdx.x & 63) << 6;
  const int tid = threadIdx.x;
  const int nl4 = tid & 15;
  const int cg = tid >> 4;
  float acc[4][16];
#pragma unroll
  for (int i = 0; i < 4; ++i)
#pragma unroll
    for (int j = 0; j < 16; ++j) acc[i][j] = 0.f;

  for (int kt = 0; kt < 4; ++kt) {
    __syncthreads();
#pragma unroll 4
    for (int i = 0; i < 16; ++i) {
      int idx = tid + 256 * i;
      int k = idx >> 6, n = idx & 63;
      xt[idx] = x[((size_t)(b * CD + kt * 64 + k)) * NB + n0 + n];
    }
#pragma unroll 4
    for (int i = 0; i < 16; ++i) {
      int q = tid + 256 * i;
      int c = q >> 4, k4 = (q & 15) * 4;
      float4 v = *(const float4*)&fc_w[(size_t)c * CD + kt * 64 + k4];
      wt[(k4 + 0) * 260 + c] = v.x;
      wt[(k4 + 1) * 260 + c] = v.y;
      wt[(k4 + 2) * 260 + c] = v.z;
      wt[(k4 + 3) * 260 + c] = v.w;
    }
    __syncthreads();
#pragma unroll 2
    for (int k = 0; k < 64; ++k) {
      float4 xv = *(const float4*)&xt[k * 64 + 4 * nl4];
#pragma unroll
      for (int j = 0; j < 4; ++j) {
        float4 wv = *(const float4*)&wt[k * 260 + 4 * cg + 64 * j];
        const float* wp = &wv.x;
#pragma unroll
        for (int l = 0; l < 4; ++l) {
          acc[0][4 * j + l] = fmaf(xv.x, wp[l], acc[0][4 * j + l]);
          acc[1][4 * j + l] = fmaf(xv.y, wp[l], acc[1][4 * j + l]);
          acc[2][4 * j + l] = fmaf(xv.z, wp[l], acc[2][4 * j + l]);
          acc[3][4 * j + l] = fmaf(xv.w, wp[l], acc[3][4 * j + l]);
        }
      }
    }
  }
#pragma unroll
  for (int i = 0; i < 4; ++i) {
    int n = n0 + 4 * nl4 + i;
    float* dst = xlin + ((size_t)(b * NB + n)) * CD;
#pragma unroll
    for (int j = 0; j < 4; ++j) {
      int c = 4 * cg + 64 * j;
      float4 bv = *(const float4*)&fc_b[c];
      float4 o;
      o.x = acc[i][4 * j + 0] + bv.x;
      o.y = acc[i][4 * j + 1] + bv.y;
      o.z = acc[i][4 * j + 2] + bv.z;
      o.w = acc[i][4 * j + 3] + bv.w;
      *(float4*)&dst[c] = o;
    }
  }
}

// insert p into sorted 24-list (ascending, strict compares -> stable, exact)
#define INSERT24(p)                                        \
  if ((p) < lst[23]) {                                     \
    lst[23] = (p);                                         \
    _Pragma("unroll")                                      \
    for (int t = 23; t >= 1; --t) {                        \
      unsigned long long a_ = lst[t - 1], b_ = lst[t];     \
      bool sw_ = b_ < a_;                                  \
      lst[t - 1] = sw_ ? b_ : a_;                          \
      lst[t] = sw_ ? a_ : b_;                              \
    }                                                      \
  }

// ---------------- K3 v8 (reverted from failed v9 compaction): m-split partial kNN;
// per-lane 4-slot candidate queue batches the sorted-insert. EXACT selection.
// NOTE (r9 lesson): capped per-row survivor lists are distribution-UNSAFE — rows with
// small sq[n] can pass >40% of candidates (r9: cap 96 overflowed -> absmax 0.22).
__global__ __launch_bounds__(512, 4) void k_distp(const unsigned* __restrict__ emb_hl,
                                                  const float* __restrict__ sq,
                                                  unsigned long long* __restrict__ part) {
  __shared__ __align__(16) unsigned char smem[51712];
  unsigned* eN = (unsigned*)smem;                        // 16384 B
  unsigned* eM = (unsigned*)(smem + 16384);              // 16384 B
  float* d2f   = (float*)(smem + 32768);                 // 16640 B (64 x 65)
  float* sqN   = (float*)(smem + 49408);                 // 256 B
  float* sqMp  = (float*)(smem + 49664);                 // 2048 B (512 m of this part)
  unsigned long long* dump = (unsigned long long*)smem;  // overlay phase 2: 49152 B (4x64x24)

  const int bid = blockIdx.x;
  const int mp = bid & 7;
  const int nt = (bid >> 3) & 63;
  const int b  = bid >> 9;
  const int n0 = nt << 6;
  const int m00 = mp << 9;   // global m base of this part
  const int tid = threadIdx.x;
  const uint4* embg = (const uint4*)emb_hl;
  const size_t bbase = (size_t)b * NB;

#pragma unroll
  for (int k = 0; k < 2; ++k) {
    int q = tid + 512 * k;
    int r = q >> 4, ch = q & 15;
    *(uint4*)&eN[r * 64 + ch * 4] = embg[(bbase + n0 + r) * 16 + ch];
  }
  if (tid < 64) sqN[tid] = sq[b * NB + n0 + tid];
  sqMp[tid] = sq[b * NB + m00 + tid];

  const int w = tid >> 6, lane = tid & 63;
  const int quad = lane >> 4, lr = lane & 15;
  const int rt = w >> 1;            // row tile 0..3
  const int ct0 = (w & 1) * 2;      // first of my 2 col tiles (of 4)
  const int rowA = rt * 16 + lr;

  const int seg = tid >> 6;         // 0..7; only seg<4 drain (16 cols each)
  const int dr = tid & 63;

  unsigned long long lst[24];
#pragma unroll
  for (int i = 0; i < 24; ++i) lst[i] = ~0ULL;
  unsigned long long q0 = 0, q1 = 0, q2 = 0, q3 = 0;  // pending-candidate queue
  int qc = 0;

  for (int ci = 0; ci < 8; ++ci) {
    const int m0 = ci << 6;  // local m offset
#pragma unroll
    for (int k = 0; k < 2; ++k) {
      int q = tid + 512 * k;
      int r = q >> 4, ch = q & 15;
      *(uint4*)&eM[r * 64 + ch * 4] = embg[(bbase + m00 + m0 + r) * 16 + ch];
    }
    __syncthreads();  // B1: eM ready AND previous drain done

    f32x4 acc0 = {0.f, 0.f, 0.f, 0.f};
    f32x4 acc1 = {0.f, 0.f, 0.f, 0.f};
#pragma unroll
    for (int kk = 0; kk < 2; ++kk) {
      const int cb = quad + 4 * kk;
      bf16x8 a_hi = *(const bf16x8*)&eN[rowA * 64 + ((cb) ^ lr) * 4];
      bf16x8 a_lo = *(const bf16x8*)&eN[rowA * 64 + ((cb + 8) ^ lr) * 4];
      int rowB0 = ct0 * 16 + lr, rowB1 = rowB0 + 16;
      bf16x8 b0_hi = *(const bf16x8*)&eM[rowB0 * 64 + ((cb) ^ lr) * 4];
      bf16x8 b0_lo = *(const bf16x8*)&eM[rowB0 * 64 + ((cb + 8) ^ lr) * 4];
      bf16x8 b1_hi = *(const bf16x8*)&eM[rowB1 * 64 + ((cb) ^ lr) * 4];
      bf16x8 b1_lo = *(const bf16x8*)&eM[rowB1 * 64 + ((cb + 8) ^ lr) * 4];
      acc0 = __builtin_amdgcn_mfma_f32_16x16x32_bf16(a_hi, b0_hi, acc0, 0, 0, 0);
      acc0 = __builtin_amdgcn_mfma_f32_16x16x32_bf16(a_hi, b0_lo, acc0, 0, 0, 0);
      acc0 = __builtin_amdgcn_mfma_f32_16x16x32_bf16(a_lo, b0_hi, acc0, 0, 0, 0);
      acc1 = __builtin_amdgcn_mfma_f32_16x16x32_bf16(a_hi, b1_hi, acc1, 0, 0, 0);
      acc1 = __builtin_amdgcn_mfma_f32_16x16x32_bf16(a_hi, b1_lo, acc1, 0, 0, 0);
      acc1 = __builtin_amdgcn_mfma_f32_16x16x32_bf16(a_lo, b1_hi, acc1, 0, 0, 0);
    }
#pragma unroll
    for (int reg = 0; reg < 4; ++reg) {
      int row = rt * 16 + quad * 4 + reg;
      int c0 = ct0 * 16 + lr, c1 = c0 + 16;
      float d20 = fmaxf(sqN[row] + sqMp[m0 + c0] - 2.f * acc0[reg], 0.f);
      float d21 = fmaxf(sqN[row] + sqMp[m0 + c1] - 2.f * acc1[reg], 0.f);
      d2f[row * 65 + c0] = d20;
      d2f[row * 65 + c1] = d21;
    }
    __syncthreads();  // B2: d2f ready (also: frag reads done -> eM restage safe)

    if (seg < 4) {  // wave-uniform branch (seg == wave id)
#pragma unroll 1
      for (int j = 0; j < 16; ++j) {
        float v = d2f[dr * 65 + seg * 16 + j];
        if (v <= 100.f) {  // exact pre-filter (rank metric == filter metric)
          unsigned long long p =
              ((unsigned long long)__float_as_uint(v) << 32) | (unsigned)(m00 + m0 + seg * 16 + j);
          q0 = (qc == 0) ? p : q0;
          q1 = (qc == 1) ? p : q1;
          q2 = (qc == 2) ? p : q2;
          q3 = (qc == 3) ? p : q3;
          ++qc;
        }
        if (__any(qc >= 4)) {  // batched flush: arrival order preserved -> semantics identical
          if (qc > 0) { INSERT24(q0) }
          if (qc > 1) { INSERT24(q1) }
          if (qc > 2) { INSERT24(q2) }
          if (qc > 3) { INSERT24(q3) }
          qc = 0;
        }
      }
    }
    // seg>=4 waves run ahead to stage next eM; B1 orders drain reads vs d2f overwrite
  }
  // final flush of pending candidates
  if (seg < 4) {
    if (qc > 0) { INSERT24(q0) }
    if (qc > 1) { INSERT24(q1) }
    if (qc > 2) { INSERT24(q2) }
    if (qc > 3) { INSERT24(q3) }
  }
  __syncthreads();  // tiles dead -> reuse as dump

  if (seg < 4) {
#pragma unroll
    for (int i = 0; i < 24; ++i) dump[((seg << 6) | dr) * 24 + i] = lst[i];
  }
  __syncthreads();

  if (tid < 64) {
    int pp[4] = {0, 0, 0, 0};
    unsigned long long h[4];
#pragma unroll
    for (int t = 0; t < 4; ++t) h[t] = dump[((t << 6) | tid) * 24];
    unsigned long long* op = part + ((size_t)bid * 64 + tid) * 24;
#pragma unroll 1
    for (int k = 0; k < 24; ++k) {
      int bs = 0;
      unsigned long long mv = h[0];
#pragma unroll
      for (int t = 1; t < 4; ++t)
        if (h[t] < mv) { mv = h[t]; bs = t; }
      op[k] = mv;  // sentinels ok; k_merge cuts
      int np = ++pp[bs];
      h[bs] = (np < 24) ? dump[((bs << 6) | tid) * 24 + np] : ~0ULL;
    }
  }
}

// ---------------- K3b: merge 8 sorted partials per row -> row_idx/row_cnt/col_cnt
__global__ __launch_bounds__(256) void k_merge(const unsigned long long* __restrict__ part,
                                               int* __restrict__ row_idx,
                                               int* __restrict__ row_cnt,
                                               int* __restrict__ col_cnt) {
  const int row = blockIdx.x * 256 + threadIdx.x;  // b*4096 + n
  const int b = row >> 12;
  const int n = row & 4095;
  const int nt = n >> 6, r = n & 63;
  const size_t gb = (size_t)(((b << 6) | nt) << 3);  // block base (b,nt,mp=0)
  unsigned long long h[8];
  int pp[8];
#pragma unroll
  for (int t = 0; t < 8; ++t) {
    h[t] = part[((gb + t) * 64 + r) * 24];
    pp[t] = 0;
  }
  int cnt = 0;
  const int base = row * KNN;
  for (int k = 0; k < 24; ++k) {
    int bs = 0;
    unsigned long long mv = h[0];
#pragma unroll
    for (int t = 1; t < 8; ++t)
      if (h[t] < mv) { mv = h[t]; bs = t; }
    if ((unsigned)(mv >> 32) > 0x42C80000u) break;  // sentinel / beyond threshold
    int mi = (int)(mv & 0xFFFFFFFFu);
    row_idx[base + cnt] = mi;
    atomicAdd(&col_cnt[(b << 12) + mi], 1);
    ++cnt;
    int np = ++pp[bs];
    h[bs] = (np < 24) ? part[((gb + bs) * 64 + r) * 24 + np] : ~0ULL;
  }
  row_cnt[row] = cnt;
#pragma unroll 4
  for (int j = cnt; j < 24; ++j) row_idx[base + j] = n;  // pad with self (valid gather idx)
}

// ---------------- K4: exclusive scan of col_cnt (16384 entries), 1 block
__global__ __launch_bounds__(256) void k_scan(const int* __restrict__ col_cnt,
                                              int* __restrict__ col_start,
                                              int* __restrict__ col_cursor) {
  __shared__ int part[256];
  const int tid = threadIdx.x;
  const int base = tid * 64;
  int s = 0;
  for (int j = 0; j < 64; ++j) s += col_cnt[base + j];
  part[tid] = s;
  __syncthreads();
  for (int off = 1; off < 256; off <<= 1) {
    int v = (tid >= off) ? part[tid - off] : 0;
    __syncthreads();
    part[tid] += v;
    __syncthreads();
  }
  int run = part[tid] - s;
  for (int j = 0; j < 64; ++j) {
    col_start[base + j] = run;
    col_cursor[base + j] = run;
    run += col_cnt[base + j];
  }
}

// ---------------- K5: fill CSC column lists
__global__ __launch_bounds__(256) void k_fill(const int* __restrict__ row_idx,
                                              const int* __restrict__ row_cnt,
                                              int* __restrict__ col_cursor,
                                              int* __restrict__ col_list) {
  const int row = blockIdx.x * 256 + threadIdx.x;
  const int b = row >> 12;
  const int cnt = row_cnt[row];
  for (int j = 0; j < cnt; ++j) {
    int m = row_idx[row * KNN + j];
    int pos = atomicAdd(&col_cursor[(b << 12) + m], 1);
    col_list[pos] = row & 4095;
  }
}

// ---------------- K6: Yd[e,c] = (sum_{m in col(e)} X_lin[m,c]) / De[e]
__global__ __launch_bounds__(256) void k_yd(const float* __restrict__ xlin,
                                            const int* __restrict__ col_cnt,
                                            const int* __restrict__ col_start,
                                            const int* __restrict__ col_list,
                                            float* __restrict__ yd) {
  const int le = threadIdx.x >> 6;
  const int c4 = threadIdx.x & 63;
  const int be = blockIdx.x * 4 + le;
  const int b = be >> 12;
  const int deg = col_cnt[be];
  const int start = col_start[be];
  float4 acc = make_float4(0.f, 0.f, 0.f, 0.f);
  int j = 0;
  for (; j + 3 < deg; j += 4) {
    int ma = col_list[start + j], mb2 = col_list[start + j + 1];
    int mc = col_list[start + j + 2], md = col_list[start + j + 3];
    float4 va = *(const float4*)&xlin[(((size_t)(b << 12) + ma) << 8) + c4 * 4];
    float4 vb = *(const float4*)&xlin[(((size_t)(b << 12) + mb2) << 8) + c4 * 4];
    float4 vc = *(const float4*)&xlin[(((size_t)(b << 12) + mc) << 8) + c4 * 4];
    float4 vd = *(const float4*)&xlin[(((size_t)(b << 12) + md) << 8) + c4 * 4];
    acc.x += (va.x + vb.x) + (vc.x + vd.x);
    acc.y += (va.y + vb.y) + (vc.y + vd.y);
    acc.z += (va.z + vb.z) + (vc.z + vd.z);
    acc.w += (va.w + vb.w) + (vc.w + vd.w);
  }
  for (; j < deg; ++j) {
    int m = col_list[start + j];
    float4 v = *(const float4*)&xlin[(((size_t)(b << 12) + m) << 8) + c4 * 4];
    acc.x += v.x; acc.y += v.y; acc.z += v.z; acc.w += v.w;
  }
  float inv = 1.f / (float)deg;
  acc.x *= inv; acc.y *= inv; acc.z *= inv; acc.w *= inv;
  *(float4*)&yd[((size_t)be << 8) + c4 * 4] = acc;
}

// ---------------- K7: g[n,c] = (sum_{e in row(n)} Yd[e,c]) / Dv[n]
__global__ __launch_bounds__(256) void k_out2(const float* __restrict__ yd,
                                              const int* __restrict__ row_idx,
                                              const int* __restrict__ row_cnt,
                                              float* __restrict__ outf) {
  const int b = blockIdx.x >> 8;
  const int nt = blockIdx.x & 255;
  const int le = threadIdx.x >> 6;
  const int c4 = threadIdx.x & 63;
  for (int ii = 0; ii < 4; ++ii) {
    int n = nt * 16 + le * 4 + ii;
    int row = (b << 12) + n;
    int cnt = row_cnt[row];
    int idx[24];
    const int4* ip = (const int4*)(row_idx + (size_t)row * KNN);
#pragma unroll
    for (int t = 0; t < 6; ++t) {
      int4 v = ip[t];
      idx[4 * t] = v.x; idx[4 * t + 1] = v.y; idx[4 * t + 2] = v.z; idx[4 * t + 3] = v.w;
    }
    float4 acc = make_float4(0.f, 0.f, 0.f, 0.f);
#pragma unroll
    for (int j = 0; j < 24; ++j) {
      float wgt = (j < cnt) ? 1.f : 0.f;
      float4 v = *(const float4*)&yd[(((size_t)(b << 12) + idx[j]) << 8) + c4 * 4];
      acc.x = fmaf(wgt, v.x, acc.x);
      acc.y = fmaf(wgt, v.y, acc.y);
      acc.z = fmaf(wgt, v.z, acc.z);
      acc.w = fmaf(wgt, v.w, acc.w);
    }
    float inv = 1.f / (float)cnt;
    acc.x *= inv; acc.y *= inv; acc.z *= inv; acc.w *= inv;
    *(float4*)&outf[((size_t)row << 8) + c4 * 4] = acc;
  }
}

// ---------------- K8: outf += x (residual, via LDS transpose); accumulate BN sums
__global__ __launch_bounds__(256) void k_res_bn(const float* __restrict__ x,
                                                float* __restrict__ outf,
                                                float* __restrict__ bn_sum,
                                                float* __restrict__ bn_sumsq) {
  __shared__ float xt[256 * 69];
  const int b = blockIdx.x >> 6;
  const int n0 = (blockIdx.x & 63) << 6;
  const int tid = threadIdx.x;
#pragma unroll 4
  for (int k = 0; k < 16; ++k) {
    int q = tid + 256 * k;
    int c = q >> 4, f = q & 15;
    float4 v = *(const float4*)&x[((size_t)(b * CD + c)) * NB + n0 + 4 * f];
    xt[c * 69 + 4 * f + 0] = v.x;
    xt[c * 69 + 4 * f + 1] = v.y;
    xt[c * 69 + 4 * f + 2] = v.z;
    xt[c * 69 + 4 * f + 3] = v.w;
  }
  __syncthreads();
  float s = 0.f, q = 0.f;
  const size_t rbase = ((size_t)((b << 12) + n0)) << 8;
#pragma unroll 4
  for (int i = 0; i < 64; ++i) {
    float v = outf[rbase + (size_t)i * 256 + tid] + xt[tid * 69 + i];
    outf[rbase + (size_t)i * 256 + tid] = v;
    s += v;
    q = fmaf(v, v, q);
  }
  atomicAdd(&bn_sum[tid], s);
  atomicAdd(&bn_sumsq[tid], q);
}

// ---------------- K9: BN scale/shift per channel
__global__ __launch_bounds__(256) void k_bn(const float* __restrict__ bn_sum,
                                            const float* __restrict__ bn_sumsq,
                                            const float* __restrict__ gamma,
                                            const float* __restrict__ beta,
                                            float* __restrict__ scale,
                                            float* __restrict__ shift) {
  const int c = threadIdx.x;
  const float inv = 1.f / 16384.f;
  float mean = bn_sum[c] * inv;
  float var = bn_sumsq[c] * inv - mean * mean;
  float sc = gamma[c] * rsqrtf(var + 1e-5f);
  scale[c] = sc;
  shift[c] = beta[c] - mean * sc;
}

// ---------------- K10: normalize + SiLU + transpose to [B,C,N]
__global__ __launch_bounds__(256) void k_write(const float* __restrict__ outf,
                                               const float* __restrict__ scale,
                                               const float* __restrict__ shift,
                                               float* __restrict__ out) {
  __shared__ float tile[64 * 257];
  __shared__ float sc[256], sh[256];
  const int b = blockIdx.x >> 6;
  const int n0 = (blockIdx.x & 63) << 6;
  const int tid = threadIdx.x;
  sc[tid] = scale[tid];
  sh[tid] = shift[tid];
  __syncthreads();
#pragma unroll 4
  for (int i = 0; i < 64; ++i) {
    int idx = tid + 256 * i;
    int n = idx >> 8, c = idx & 255;
    float v = outf[(((size_t)(b << 12) + n0 + n) << 8) + c];
    v = fmaf(v, sc[c], sh[c]);
    float w = v / (1.f + expf(-v));  // SiLU
    tile[n * 257 + c] = w;
  }
  __syncthreads();
  const int nl = tid & 63;
  const int cg = tid >> 6;
#pragma unroll 4
  for (int j = 0; j < 64; ++j) {
    int c = cg * 64 + j;
    out[((size_t)(b * CD + c)) * NB + n0 + nl] = tile[nl * 257 + c];
  }
}

extern "C" void kernel_launch(void* const* d_in, const int* in_sizes, int n_in,
                              void* d_out, int out_size, void* d_ws, size_t ws_size,
                              hipStream_t stream) {
  const float* x      = (const float*)d_in[0];
  const float* fc_w   = (const float*)d_in[1];
  const float* fc_b   = (const float*)d_in[2];
  const float* dist_w = (const float*)d_in[3];
  const float* gamma  = (const float*)d_in[4];
  const float* beta   = (const float*)d_in[5];
  float* out = (float*)d_out;
  char* ws = (char*)d_ws;

  const size_t OFF_EHL   = 0;                   // 4 MB
  const size_t OFF_XLIN  = (size_t)4 << 20;     // 16 MB
  const size_t OFF_YD    = (size_t)20 << 20;    // 16 MB (part buffer overlays yd+outf: both dead then)
  const size_t OFF_OUTF  = (size_t)36 << 20;    // 16 MB
  const size_t OFF_SQ    = (size_t)52 << 20;
  const size_t OFF_RIDX  = OFF_SQ + 65536;
  const size_t OFF_RCNT  = OFF_RIDX + 1572864;
  const size_t OFF_CCNT  = OFF_RCNT + 65536;
  const size_t OFF_CSTART = OFF_CCNT + 65536;
  const size_t OFF_CCUR  = OFF_CSTART + 65536;
  const size_t OFF_CLIST = OFF_CCUR + 65536;
  const size_t OFF_BNS   = OFF_CLIST + 1572864;
  const size_t OFF_BNQ   = OFF_BNS + 1024;
  const size_t OFF_SCALE = OFF_BNQ + 1024;
  const size_t OFF_SHIFT = OFF_SCALE + 1024;
  const size_t TOTAL = OFF_SHIFT + 1024;
  if (ws_size < TOTAL) return;

  unsigned* emb_hl = (unsigned*)(ws + OFF_EHL);
  float* xlin  = (float*)(ws + OFF_XLIN);
  float* yd    = (float*)(ws + OFF_YD);
  float* outf  = (float*)(ws + OFF_OUTF);
  unsigned long long* part = (unsigned long long*)(ws + OFF_YD);  // 25.2 MB overlay (yd+outf dead here)
  float* sq    = (float*)(ws + OFF_SQ);
  int* row_idx = (int*)(ws + OFF_RIDX);
  int* row_cnt = (int*)(ws + OFF_RCNT);
  int* col_cnt = (int*)(ws + OFF_CCNT);
  int* col_start = (int*)(ws + OFF_CSTART);
  int* col_cursor = (int*)(ws + OFF_CCUR);
  int* col_list = (int*)(ws + OFF_CLIST);
  float* bn_sum = (float*)(ws + OFF_BNS);
  float* bn_sumsq = (float*)(ws + OFF_BNQ);
  float* scale = (float*)(ws + OFF_SCALE);
  float* shift = (float*)(ws + OFF_SHIFT);

  hipMemsetAsync(col_cnt, 0, 65536, stream);
  hipMemsetAsync(bn_sum, 0, 2048, stream);

  k_emb<<<256, 256, 0, stream>>>(x, dist_w, emb_hl, sq);
  k_xlin<<<256, 256, 0, stream>>>(x, fc_w, fc_b, xlin);
  k_distp<<<2048, 512, 0, stream>>>(emb_hl, sq, part);
  k_merge<<<64, 256, 0, stream>>>(part, row_idx, row_cnt, col_cnt);
  k_scan<<<1, 256, 0, stream>>>(col_cnt, col_start, col_cursor);
  k_fill<<<64, 256, 0, stream>>>(row_idx, row_cnt, col_cursor, col_list);
  k_yd<<<4096, 256, 0, stream>>>(xlin, col_cnt, col_start, col_list, yd);
  k_out2<<<1024, 256, 0, stream>>>(yd, row_idx, row_cnt, outf);
  k_res_bn<<<256, 256, 0, stream>>>(x, outf, bn_sum, bn_sumsq);
  k_bn<<<1, 256, 0, stream>>>(bn_sum, bn_sumsq, gamma, beta, scale, shift);
  k_write<<<256, 256, 0, stream>>>(outf, scale, shift, out);
}